// Round 1
// baseline (6880.628 us; speedup 1.0000x reference)
//
#include <hip/hip_runtime.h>
#include <math.h>

#define D_MODEL 512
#define SEQ     2048
#define BATCH   4
#define NH      8
#define HD      64
#define CHUNK   32
#define NCHUNK  64

__device__ __forceinline__ float sigmoidf_(float x){ return 1.f/(1.f+expf(-x)); }

// ---------- block reductions (blockDim multiple of 64) ----------
__device__ __forceinline__ float block_sum(float v, float* lds){
  #pragma unroll
  for (int o=32;o>0;o>>=1) v += __shfl_xor(v,o);
  int w = threadIdx.x>>6, l = threadIdx.x&63;
  if (l==0) lds[w]=v;
  __syncthreads();
  float t=0.f; int nw = blockDim.x>>6;
  for (int i=0;i<nw;++i) t+=lds[i];
  __syncthreads();
  return t;
}

// ---------- shift ----------
__global__ void shift_k(const float* __restrict__ x, const float* __restrict__ xp,
                        const float* __restrict__ mu, float* __restrict__ out, int n){
  int i = blockIdx.x*blockDim.x + threadIdx.x;
  if (i<n){ float m = mu[0]; out[i] = m*x[i] + (1.f-m)*xp[i]; }
}

// ---------- generic GEMM: Y[M,Nd] = X[M,K] @ W[Nd,K]^T + bias ----------
template<int ACT>
__global__ __launch_bounds__(256) void gemm_k(const float* __restrict__ X, const float* __restrict__ W,
    const float* __restrict__ bias, float* __restrict__ Y, int M, int Nd, int K){
  __shared__ float Xs[64][17];
  __shared__ float Ws[64][17];
  const int bn = blockIdx.x, bm = blockIdx.y;
  const int tid = threadIdx.x;
  const int tx = tid & 15, ty = tid >> 4;
  const int lr = tid >> 2, lc = (tid & 3) * 4;
  float acc[4][4] = {};
  const float* Xb = X + (size_t)bm*64*K;
  const float* Wb = W + (size_t)bn*64*K;
  for (int k0 = 0; k0 < K; k0 += 16){
    float4 xv = *(const float4*)(Xb + (size_t)lr*K + k0 + lc);
    float4 wv = *(const float4*)(Wb + (size_t)lr*K + k0 + lc);
    Xs[lr][lc]=xv.x; Xs[lr][lc+1]=xv.y; Xs[lr][lc+2]=xv.z; Xs[lr][lc+3]=xv.w;
    Ws[lr][lc]=wv.x; Ws[lr][lc+1]=wv.y; Ws[lr][lc+2]=wv.z; Ws[lr][lc+3]=wv.w;
    __syncthreads();
    #pragma unroll
    for (int kk=0;kk<16;++kk){
      float xr[4], wr[4];
      #pragma unroll
      for (int i=0;i<4;++i) xr[i] = Xs[ty*4+i][kk];
      #pragma unroll
      for (int j=0;j<4;++j) wr[j] = Ws[tx*4+j][kk];
      #pragma unroll
      for (int i=0;i<4;++i)
        #pragma unroll
        for (int j=0;j<4;++j)
          acc[i][j] += xr[i]*wr[j];
    }
    __syncthreads();
  }
  #pragma unroll
  for (int i=0;i<4;++i){
    int rr = bm*64 + ty*4 + i;
    #pragma unroll
    for (int j=0;j<4;++j){
      int cc = bn*64 + tx*4 + j;
      float v = acc[i][j] + bias[cc];
      if (ACT==1) v = fmaxf(v, 0.f);
      Y[(size_t)rr*Nd + cc] = v;
    }
  }
}

// ---------- attention: one block per (q, h, b), scores row in LDS ----------
__global__ __launch_bounds__(256) void attn_k(const float* __restrict__ qkv, float* __restrict__ ao){
  __shared__ float qs[HD];
  __shared__ float sc[SEQ];
  __shared__ float redm[4], reds[4];
  __shared__ float osum[4][HD];
  const int qi = blockIdx.x, h = blockIdx.y, b = blockIdx.z;
  const int tid = threadIdx.x;
  const size_t rs = 3*D_MODEL;
  const float* qrow = qkv + ((size_t)b*SEQ + qi)*rs + h*HD;
  if (tid < HD) qs[tid] = qrow[tid];
  __syncthreads();
  const float* Kb = qkv + (size_t)b*SEQ*rs + D_MODEL + h*HD;
  for (int j = tid; j < SEQ; j += 256){
    const float4* kr = (const float4*)(Kb + (size_t)j*rs);
    float d = 0.f;
    #pragma unroll
    for (int t=0;t<16;++t){
      float4 kv = kr[t];
      d += qs[4*t]*kv.x + qs[4*t+1]*kv.y + qs[4*t+2]*kv.z + qs[4*t+3]*kv.w;
    }
    sc[j] = d * 0.125f;
  }
  __syncthreads();
  float m = -INFINITY;
  for (int j=tid;j<SEQ;j+=256) m = fmaxf(m, sc[j]);
  #pragma unroll
  for (int o=32;o>0;o>>=1) m = fmaxf(m, __shfl_xor(m,o));
  const int w = tid>>6, l = tid&63;
  if (l==0) redm[w]=m;
  __syncthreads();
  m = fmaxf(fmaxf(redm[0],redm[1]),fmaxf(redm[2],redm[3]));
  float s = 0.f;
  for (int j=tid;j<SEQ;j+=256){ float e = expf(sc[j]-m); sc[j]=e; s += e; }
  #pragma unroll
  for (int o=32;o>0;o>>=1) s += __shfl_xor(s,o);
  if (l==0) reds[w]=s;
  __syncthreads();   // also makes sc[] exp-writes visible for phase 3
  const float ssum = reds[0]+reds[1]+reds[2]+reds[3];
  const float* Vb = qkv + (size_t)b*SEQ*rs + 2*D_MODEL + h*HD;
  float acc = 0.f;
  const int j0 = w*512;
  for (int j=j0;j<j0+512;++j) acc += sc[j] * Vb[(size_t)j*rs + l];
  osum[w][l] = acc;
  __syncthreads();
  if (tid < HD){
    float o = (osum[0][tid]+osum[1][tid]+osum[2][tid]+osum[3][tid]) / ssum;
    ao[((size_t)b*SEQ + qi)*D_MODEL + h*HD + tid] = o;
  }
}

// ---------- LayerNorm over D=512; MODE 0: A, 1: A+B, 2: sigmoid(A)*B ----------
template<int MODE>
__global__ __launch_bounds__(256) void ln_k(const float* __restrict__ A, const float* __restrict__ Bp,
    const float* __restrict__ g, const float* __restrict__ be, float* __restrict__ out){
  __shared__ float lds[4];
  const size_t off = (size_t)blockIdx.x * D_MODEL;
  const int tid = threadIdx.x;
  float a0 = A[off+tid], a1 = A[off+tid+256];
  if (MODE==1){ a0 += Bp[off+tid]; a1 += Bp[off+tid+256]; }
  if (MODE==2){ a0 = sigmoidf_(a0)*Bp[off+tid]; a1 = sigmoidf_(a1)*Bp[off+tid+256]; }
  float mean = block_sum(a0+a1, lds) * (1.f/512.f);
  float d0=a0-mean, d1=a1-mean;
  float var = block_sum(d0*d0+d1*d1, lds) * (1.f/512.f);
  float rstd = rsqrtf(var + 1e-5f);
  out[off+tid]     = d0*rstd*g[tid]     + be[tid];
  out[off+tid+256] = d1*rstd*g[tid+256] + be[tid+256];
}

// ---------- scan prep: decay, u = e*x, row stats dm (mean decay), es (sum e) ----------
__global__ __launch_bounds__(256) void scanprep_k(const float* __restrict__ x1, const float* __restrict__ tm,
    float* __restrict__ decay, float* __restrict__ u, float* __restrict__ dm, float* __restrict__ es){
  __shared__ float lds[4];
  const size_t row = blockIdx.x;
  const size_t off = row * D_MODEL;
  const int tid = threadIdx.x;
  float x0 = x1[off+tid], xv1 = x1[off+tid+256];
  float d0 = sigmoidf_(x0*tm[tid]), d1 = sigmoidf_(xv1*tm[tid+256]);
  float e0 = expf(x0), e1 = expf(xv1);
  decay[off+tid]=d0; decay[off+tid+256]=d1;
  u[off+tid]=e0*x0;  u[off+tid+256]=e1*xv1;
  float dsum = block_sum(d0+d1, lds);
  float esum = block_sum(e0+e1, lds);
  if (tid==0){ dm[row]=dsum*(1.f/512.f); es[row]=esum; }
}

// ---------- scalar 'a' scan per batch: Hillis-Steele over 256 chunks of 8 ----------
__global__ __launch_bounds__(256) void ascan_k(const float* __restrict__ dm, const float* __restrict__ es,
                                               float* __restrict__ a_out){
  __shared__ float sG[256], sU[256];
  const int b = blockIdx.x, tid = threadIdx.x;
  const float* dmb = dm + (size_t)b*SEQ;
  const float* esb = es + (size_t)b*SEQ;
  const int t0 = tid*8;
  float gi[8], ui[8];
  #pragma unroll
  for (int i=0;i<8;++i){ gi[i]=dmb[t0+i]; ui[i]=esb[t0+i]; }
  float G=1.f, U=0.f;
  #pragma unroll
  for (int i=0;i<8;++i){ U = gi[i]*U + ui[i]; G *= gi[i]; }
  sG[tid]=G; sU[tid]=U;
  __syncthreads();
  for (int off=1; off<256; off<<=1){
    float pg=1.f, pu=0.f;
    bool act = tid >= off;
    if (act){ pg = sG[tid-off]; pu = sU[tid-off]; }
    __syncthreads();
    if (act){ sU[tid] = sG[tid]*pu + sU[tid]; sG[tid] = sG[tid]*pg; }
    __syncthreads();
  }
  float a = (tid==0) ? 0.f : sU[tid-1];
  #pragma unroll
  for (int i=0;i<8;++i){ a = gi[i]*a + ui[i]; a_out[(size_t)b*SEQ + t0 + i] = a; }
}

// ---------- b scan: chunked (64 chunks x 32 steps), per-channel ----------
__global__ __launch_bounds__(512) void bscan_p1(const float* __restrict__ decay, const float* __restrict__ u,
    float* __restrict__ Gc, float* __restrict__ Uc){
  const int c = blockIdx.x, b = blockIdx.y, d = threadIdx.x;
  size_t base = ((size_t)b*SEQ + (size_t)c*CHUNK)*D_MODEL + d;
  float G=1.f, U=0.f;
  for (int i=0;i<CHUNK;++i){
    float g  = decay[base + (size_t)i*D_MODEL];
    float uu = u[base + (size_t)i*D_MODEL];
    U = g*U + uu; G = g*G;
  }
  size_t idx = ((size_t)b*NCHUNK + c)*D_MODEL + d;
  Gc[idx]=G; Uc[idx]=U;
}
__global__ __launch_bounds__(512) void bscan_p2(const float* __restrict__ Gc, const float* __restrict__ Uc,
                                                float* __restrict__ binit){
  const int b = blockIdx.x, d = threadIdx.x;
  float cur = 0.f;
  for (int c=0;c<NCHUNK;++c){
    size_t idx = ((size_t)b*NCHUNK + c)*D_MODEL + d;
    binit[idx] = cur;
    cur = Gc[idx]*cur + Uc[idx];
  }
}
__global__ __launch_bounds__(512) void bscan_p3(const float* __restrict__ decay, const float* __restrict__ u,
    const float* __restrict__ binit, const float* __restrict__ a, float* __restrict__ outs){
  const int c = blockIdx.x, b = blockIdx.y, d = threadIdx.x;
  size_t base = ((size_t)b*SEQ + (size_t)c*CHUNK)*D_MODEL + d;
  float bv = binit[((size_t)b*NCHUNK + c)*D_MODEL + d];
  for (int i=0;i<CHUNK;++i){
    float g  = decay[base + (size_t)i*D_MODEL];
    float uu = u[base + (size_t)i*D_MODEL];
    bv = g*bv + uu;
    float av = a[(size_t)b*SEQ + (size_t)c*CHUNK + i];
    outs[base + (size_t)i*D_MODEL] = bv / (av + 1e-8f);
  }
}

extern "C" void kernel_launch(void* const* d_in, const int* in_sizes, int n_in,
                              void* d_out, int out_size, void* d_ws, size_t ws_size,
                              hipStream_t stream){
  const float* x     = (const float*)d_in[0];
  const float* xp    = (const float*)d_in[1];
  const float* mu    = (const float*)d_in[2];
  const float* in_w  = (const float*)d_in[3];
  const float* in_b  = (const float*)d_in[4];
  const float* out_w = (const float*)d_in[5];
  const float* out_b = (const float*)d_in[6];
  const float* ln1_g = (const float*)d_in[7];
  const float* ln1_b = (const float*)d_in[8];
  const float* tm    = (const float*)d_in[9];
  const float* sm_g  = (const float*)d_in[10];
  const float* sm_b  = (const float*)d_in[11];
  const float* wr_w  = (const float*)d_in[12];
  const float* wr_b  = (const float*)d_in[13];
  const float* wv_w  = (const float*)d_in[14];
  const float* wv_b  = (const float*)d_in[15];
  const float* sc_g  = (const float*)d_in[16];
  const float* sc_b  = (const float*)d_in[17];
  const float* ln2_g = (const float*)d_in[18];
  const float* ln2_b = (const float*)d_in[19];
  const float* w1    = (const float*)d_in[20];
  const float* b1    = (const float*)d_in[21];
  const float* w2    = (const float*)d_in[22];
  const float* b2    = (const float*)d_in[23];
  const float* ln3_g = (const float*)d_in[24];
  const float* ln3_b = (const float*)d_in[25];
  float* out = (float*)d_out;
  float* ws  = (float*)d_ws;

  const size_t N = (size_t)BATCH*SEQ*D_MODEL;   // 4,194,304
  float* S0 = ws;
  float* S1 = ws + N;
  float* S2 = ws + 2*N;
  float* S3 = ws + 3*N;
  float* S4 = ws + 4*N;
  float* EX = ws + 5*N;
  float* dm    = EX;
  float* es    = EX + (size_t)BATCH*SEQ;
  float* aarr  = EX + 2*(size_t)BATCH*SEQ;
  float* Gc    = EX + 3*(size_t)BATCH*SEQ;
  float* Uc    = Gc + (size_t)BATCH*NCHUNK*D_MODEL;
  float* binit = Uc + (size_t)BATCH*NCHUNK*D_MODEL;

  const int M = BATCH*SEQ;  // 8192

  // 1. shifted -> S0
  shift_k<<<(int)((N+255)/256), 256, 0, stream>>>(x, xp, mu, S0, (int)N);
  // 2. qkv = shifted @ in_proj_w.T + b -> S1..S3
  gemm_k<0><<<dim3(1536/64, M/64), 256, 0, stream>>>(S0, in_w, in_b, S1, M, 1536, 512);
  // 3. attention -> S4
  attn_k<<<dim3(SEQ, NH, BATCH), 256, 0, stream>>>(S1, S4);
  // 4. attn out proj -> S1
  gemm_k<0><<<dim3(512/64, M/64), 256, 0, stream>>>(S4, out_w, out_b, S1, M, 512, 512);
  // 5. x1 = LN(shifted + attnproj) -> S2
  ln_k<1><<<M, 256, 0, stream>>>(S0, S1, ln1_g, ln1_b, S2);
  // 6. scan prep: decay -> S0, u -> S1, dm/es
  scanprep_k<<<M, 256, 0, stream>>>(S2, tm, S0, S1, dm, es);
  // 7. 'a' scan
  ascan_k<<<BATCH, 256, 0, stream>>>(dm, es, aarr);
  // 8-10. 'b' chunked scan -> outs S3
  bscan_p1<<<dim3(NCHUNK, BATCH), 512, 0, stream>>>(S0, S1, Gc, Uc);
  bscan_p2<<<BATCH, 512, 0, stream>>>(Gc, Uc, binit);
  bscan_p3<<<dim3(NCHUNK, BATCH), 512, 0, stream>>>(S0, S1, binit, aarr, S3);
  // 11. merged = LN(outs) -> S4
  ln_k<0><<<M, 256, 0, stream>>>(S3, nullptr, sm_g, sm_b, S4);
  // 12. r -> S0, v2 -> S1
  gemm_k<0><<<dim3(512/64, M/64), 256, 0, stream>>>(S4, wr_w, wr_b, S0, M, 512, 512);
  gemm_k<0><<<dim3(512/64, M/64), 256, 0, stream>>>(S4, wv_w, wv_b, S1, M, 512, 512);
  // 13. coupled = LN(sigmoid(r)*v2) -> S3
  ln_k<2><<<M, 256, 0, stream>>>(S0, S1, sc_g, sc_b, S3);
  // 14. x2 = LN(x1 + coupled) -> S0
  ln_k<1><<<M, 256, 0, stream>>>(S2, S3, ln2_g, ln2_b, S0);
  // 15. hidden = relu(x2 @ w1.T + b1) -> S1 (spans S1..S4)
  gemm_k<1><<<dim3(2048/64, M/64), 256, 0, stream>>>(S0, w1, b1, S1, M, 2048, 512);
  // 16. ffnout = hidden @ w2.T + b2 -> out (temp)
  gemm_k<0><<<dim3(512/64, M/64), 256, 0, stream>>>(S1, w2, b2, out, M, 512, 2048);
  // 17. final: LN(x2 + ffnout) -> out (per-thread in-place safe)
  ln_k<1><<<M, 256, 0, stream>>>(S0, out, ln3_g, ln3_b, out);
}

// Round 2
// 2427.920 us; speedup vs baseline: 2.8340x; 2.8340x over previous
//
#include <hip/hip_runtime.h>
#include <math.h>

#define D_MODEL 512
#define SEQ     2048
#define BATCH   4
#define NH      8
#define HD      64
#define CHUNK   32
#define NCHUNK  64

__device__ __forceinline__ float sigmoidf_(float x){ return 1.f/(1.f+expf(-x)); }

// ---------- block reductions (blockDim multiple of 64) ----------
__device__ __forceinline__ float block_sum(float v, float* lds){
  #pragma unroll
  for (int o=32;o>0;o>>=1) v += __shfl_xor(v,o);
  int w = threadIdx.x>>6, l = threadIdx.x&63;
  if (l==0) lds[w]=v;
  __syncthreads();
  float t=0.f; int nw = blockDim.x>>6;
  for (int i=0;i<nw;++i) t+=lds[i];
  __syncthreads();
  return t;
}

// ---------- shift ----------
__global__ void shift_k(const float* __restrict__ x, const float* __restrict__ xp,
                        const float* __restrict__ mu, float* __restrict__ out, int n){
  int i = blockIdx.x*blockDim.x + threadIdx.x;
  if (i<n){ float m = mu[0]; out[i] = m*x[i] + (1.f-m)*xp[i]; }
}

// ---------- generic GEMM: Y[M,Nd] = X[M,K] @ W[Nd,K]^T + bias ----------
template<int ACT>
__global__ __launch_bounds__(256) void gemm_k(const float* __restrict__ X, const float* __restrict__ W,
    const float* __restrict__ bias, float* __restrict__ Y, int M, int Nd, int K){
  __shared__ float Xs[64][17];
  __shared__ float Ws[64][17];
  const int bn = blockIdx.x, bm = blockIdx.y;
  const int tid = threadIdx.x;
  const int tx = tid & 15, ty = tid >> 4;
  const int lr = tid >> 2, lc = (tid & 3) * 4;
  float acc[4][4] = {};
  const float* Xb = X + (size_t)bm*64*K;
  const float* Wb = W + (size_t)bn*64*K;
  for (int k0 = 0; k0 < K; k0 += 16){
    float4 xv = *(const float4*)(Xb + (size_t)lr*K + k0 + lc);
    float4 wv = *(const float4*)(Wb + (size_t)lr*K + k0 + lc);
    Xs[lr][lc]=xv.x; Xs[lr][lc+1]=xv.y; Xs[lr][lc+2]=xv.z; Xs[lr][lc+3]=xv.w;
    Ws[lr][lc]=wv.x; Ws[lr][lc+1]=wv.y; Ws[lr][lc+2]=wv.z; Ws[lr][lc+3]=wv.w;
    __syncthreads();
    #pragma unroll
    for (int kk=0;kk<16;++kk){
      float xr[4], wr[4];
      #pragma unroll
      for (int i=0;i<4;++i) xr[i] = Xs[ty*4+i][kk];
      #pragma unroll
      for (int j=0;j<4;++j) wr[j] = Ws[tx*4+j][kk];
      #pragma unroll
      for (int i=0;i<4;++i)
        #pragma unroll
        for (int j=0;j<4;++j)
          acc[i][j] += xr[i]*wr[j];
    }
    __syncthreads();
  }
  #pragma unroll
  for (int i=0;i<4;++i){
    int rr = bm*64 + ty*4 + i;
    #pragma unroll
    for (int j=0;j<4;++j){
      int cc = bn*64 + tx*4 + j;
      float v = acc[i][j] + bias[cc];
      if (ACT==1) v = fmaxf(v, 0.f);
      Y[(size_t)rr*Nd + cc] = v;
    }
  }
}

// ---------- flash attention: block = (64 q-rows, h, b), 256 threads ----------
// Layouts (pad 68 floats => row stride 272B = 16B-aligned, bank-stride 4):
//  Qs[64][68], Ks[64][68] natural rows; Vt[64][68] = V transposed (hd x seq);
//  Ps[64][68] probabilities. Micro-tile 4x4: rows i*16+ty, cols j*16+tx.
__global__ __launch_bounds__(256) void fattn_k(const float* __restrict__ qkv, float* __restrict__ ao){
  __shared__ __align__(16) float Qs[64][68];
  __shared__ __align__(16) float Ks[64][68];
  __shared__ __align__(16) float Vt[64][68];
  __shared__ __align__(16) float Ps[64][68];
  const int qt = blockIdx.x, h = blockIdx.y, b = blockIdx.z;
  const int tid = threadIdx.x;
  const int tx = tid & 15, ty = tid >> 4;
  const size_t rs = 3*D_MODEL;
  const float* Qg = qkv + ((size_t)b*SEQ + (size_t)qt*64)*rs + h*HD;
  const float* Kg = qkv + (size_t)b*SEQ*rs + D_MODEL   + h*HD;
  const float* Vg = qkv + (size_t)b*SEQ*rs + 2*D_MODEL + h*HD;

  // stage Q once, folding in the 1/sqrt(hd)=0.125 scale
  {
    const int r = tid >> 2, cb = tid & 3;
    const float4* src = (const float4*)(Qg + (size_t)r*rs + cb*16);
    #pragma unroll
    for (int s = 0; s < 4; ++s){
      float4 v = src[s];
      v.x *= 0.125f; v.y *= 0.125f; v.z *= 0.125f; v.w *= 0.125f;
      *(float4*)&Qs[r][cb*16 + s*4] = v;
    }
  }

  float o[4][4] = {};
  float m[4] = {-INFINITY,-INFINITY,-INFINITY,-INFINITY};
  float l[4] = {};

  for (int kt = 0; kt < SEQ/64; ++kt){
    __syncthreads();   // prev PV done (and Q staged on first iter)
    // stage K tile (rows) and V tile (transposed)
    {
      const int r = tid >> 2, cb = tid & 3;
      const float4* ks = (const float4*)(Kg + (size_t)(kt*64 + r)*rs + cb*16);
      const float4* vs = (const float4*)(Vg + (size_t)(kt*64 + r)*rs + cb*16);
      float4 k0=ks[0], k1=ks[1], k2=ks[2], k3=ks[3];
      float4 v0=vs[0], v1=vs[1], v2=vs[2], v3=vs[3];
      *(float4*)&Ks[r][cb*16 + 0]  = k0;
      *(float4*)&Ks[r][cb*16 + 4]  = k1;
      *(float4*)&Ks[r][cb*16 + 8]  = k2;
      *(float4*)&Ks[r][cb*16 + 12] = k3;
      const int c0 = cb*16;
      Vt[c0+ 0][r]=v0.x; Vt[c0+ 1][r]=v0.y; Vt[c0+ 2][r]=v0.z; Vt[c0+ 3][r]=v0.w;
      Vt[c0+ 4][r]=v1.x; Vt[c0+ 5][r]=v1.y; Vt[c0+ 6][r]=v1.z; Vt[c0+ 7][r]=v1.w;
      Vt[c0+ 8][r]=v2.x; Vt[c0+ 9][r]=v2.y; Vt[c0+10][r]=v2.z; Vt[c0+11][r]=v2.w;
      Vt[c0+12][r]=v3.x; Vt[c0+13][r]=v3.y; Vt[c0+14][r]=v3.z; Vt[c0+15][r]=v3.w;
    }
    __syncthreads();

    // S = Q K^T (scaled), 4x4 per thread
    float s[4][4] = {};
    #pragma unroll
    for (int kb = 0; kb < 16; ++kb){
      float4 qv[4], kv[4];
      #pragma unroll
      for (int i=0;i<4;++i) qv[i] = *(const float4*)&Qs[i*16+ty][kb*4];
      #pragma unroll
      for (int j=0;j<4;++j) kv[j] = *(const float4*)&Ks[j*16+tx][kb*4];
      #pragma unroll
      for (int i=0;i<4;++i)
        #pragma unroll
        for (int j=0;j<4;++j)
          s[i][j] += qv[i].x*kv[j].x + qv[i].y*kv[j].y + qv[i].z*kv[j].z + qv[i].w*kv[j].w;
    }

    // online softmax per row (rows shared by the 16-lane tx-group)
    #pragma unroll
    for (int i=0;i<4;++i){
      float rm = fmaxf(fmaxf(s[i][0],s[i][1]), fmaxf(s[i][2],s[i][3]));
      rm = fmaxf(rm, __shfl_xor(rm, 1));
      rm = fmaxf(rm, __shfl_xor(rm, 2));
      rm = fmaxf(rm, __shfl_xor(rm, 4));
      rm = fmaxf(rm, __shfl_xor(rm, 8));
      float mnew = fmaxf(m[i], rm);
      float sc = expf(m[i] - mnew);
      float p0 = expf(s[i][0]-mnew), p1 = expf(s[i][1]-mnew);
      float p2 = expf(s[i][2]-mnew), p3 = expf(s[i][3]-mnew);
      float rsum = p0+p1+p2+p3;
      rsum += __shfl_xor(rsum, 1);
      rsum += __shfl_xor(rsum, 2);
      rsum += __shfl_xor(rsum, 4);
      rsum += __shfl_xor(rsum, 8);
      l[i] = l[i]*sc + rsum;
      m[i] = mnew;
      #pragma unroll
      for (int j=0;j<4;++j) o[i][j] *= sc;
      const int ri = i*16+ty;
      Ps[ri][0*16+tx] = p0;
      Ps[ri][1*16+tx] = p1;
      Ps[ri][2*16+tx] = p2;
      Ps[ri][3*16+tx] = p3;
    }
    __syncthreads();

    // O += P V   (Vt is [hd][seq-tile])
    #pragma unroll
    for (int kb = 0; kb < 16; ++kb){
      float4 pv[4], vv[4];
      #pragma unroll
      for (int i=0;i<4;++i) pv[i] = *(const float4*)&Ps[i*16+ty][kb*4];
      #pragma unroll
      for (int j=0;j<4;++j) vv[j] = *(const float4*)&Vt[j*16+tx][kb*4];
      #pragma unroll
      for (int i=0;i<4;++i)
        #pragma unroll
        for (int j=0;j<4;++j)
          o[i][j] += pv[i].x*vv[j].x + pv[i].y*vv[j].y + pv[i].z*vv[j].z + pv[i].w*vv[j].w;
    }
  }

  // epilogue
  #pragma unroll
  for (int i=0;i<4;++i){
    float inv = 1.f / l[i];
    const size_t row = (size_t)b*SEQ + (size_t)qt*64 + i*16+ty;
    #pragma unroll
    for (int j=0;j<4;++j)
      ao[row*D_MODEL + h*HD + j*16+tx] = o[i][j]*inv;
  }
}

// ---------- LayerNorm over D=512; MODE 0: A, 1: A+B, 2: sigmoid(A)*B ----------
template<int MODE>
__global__ __launch_bounds__(256) void ln_k(const float* __restrict__ A, const float* __restrict__ Bp,
    const float* __restrict__ g, const float* __restrict__ be, float* __restrict__ out){
  __shared__ float lds[4];
  const size_t off = (size_t)blockIdx.x * D_MODEL;
  const int tid = threadIdx.x;
  float a0 = A[off+tid], a1 = A[off+tid+256];
  if (MODE==1){ a0 += Bp[off+tid]; a1 += Bp[off+tid+256]; }
  if (MODE==2){ a0 = sigmoidf_(a0)*Bp[off+tid]; a1 = sigmoidf_(a1)*Bp[off+tid+256]; }
  float mean = block_sum(a0+a1, lds) * (1.f/512.f);
  float d0=a0-mean, d1=a1-mean;
  float var = block_sum(d0*d0+d1*d1, lds) * (1.f/512.f);
  float rstd = rsqrtf(var + 1e-5f);
  out[off+tid]     = d0*rstd*g[tid]     + be[tid];
  out[off+tid+256] = d1*rstd*g[tid+256] + be[tid+256];
}

// ---------- scan prep ----------
__global__ __launch_bounds__(256) void scanprep_k(const float* __restrict__ x1, const float* __restrict__ tm,
    float* __restrict__ decay, float* __restrict__ u, float* __restrict__ dm, float* __restrict__ es){
  __shared__ float lds[4];
  const size_t row = blockIdx.x;
  const size_t off = row * D_MODEL;
  const int tid = threadIdx.x;
  float x0 = x1[off+tid], xv1 = x1[off+tid+256];
  float d0 = sigmoidf_(x0*tm[tid]), d1 = sigmoidf_(xv1*tm[tid+256]);
  float e0 = expf(x0), e1 = expf(xv1);
  decay[off+tid]=d0; decay[off+tid+256]=d1;
  u[off+tid]=e0*x0;  u[off+tid+256]=e1*xv1;
  float dsum = block_sum(d0+d1, lds);
  float esum = block_sum(e0+e1, lds);
  if (tid==0){ dm[row]=dsum*(1.f/512.f); es[row]=esum; }
}

// ---------- scalar 'a' scan per batch ----------
__global__ __launch_bounds__(256) void ascan_k(const float* __restrict__ dm, const float* __restrict__ es,
                                               float* __restrict__ a_out){
  __shared__ float sG[256], sU[256];
  const int b = blockIdx.x, tid = threadIdx.x;
  const float* dmb = dm + (size_t)b*SEQ;
  const float* esb = es + (size_t)b*SEQ;
  const int t0 = tid*8;
  float gi[8], ui[8];
  #pragma unroll
  for (int i=0;i<8;++i){ gi[i]=dmb[t0+i]; ui[i]=esb[t0+i]; }
  float G=1.f, U=0.f;
  #pragma unroll
  for (int i=0;i<8;++i){ U = gi[i]*U + ui[i]; G *= gi[i]; }
  sG[tid]=G; sU[tid]=U;
  __syncthreads();
  for (int off=1; off<256; off<<=1){
    float pg=1.f, pu=0.f;
    bool act = tid >= off;
    if (act){ pg = sG[tid-off]; pu = sU[tid-off]; }
    __syncthreads();
    if (act){ sU[tid] = sG[tid]*pu + sU[tid]; sG[tid] = sG[tid]*pg; }
    __syncthreads();
  }
  float a = (tid==0) ? 0.f : sU[tid-1];
  #pragma unroll
  for (int i=0;i<8;++i){ a = gi[i]*a + ui[i]; a_out[(size_t)b*SEQ + t0 + i] = a; }
}

// ---------- b scan: chunked ----------
__global__ __launch_bounds__(512) void bscan_p1(const float* __restrict__ decay, const float* __restrict__ u,
    float* __restrict__ Gc, float* __restrict__ Uc){
  const int c = blockIdx.x, b = blockIdx.y, d = threadIdx.x;
  size_t base = ((size_t)b*SEQ + (size_t)c*CHUNK)*D_MODEL + d;
  float G=1.f, U=0.f;
  for (int i=0;i<CHUNK;++i){
    float g  = decay[base + (size_t)i*D_MODEL];
    float uu = u[base + (size_t)i*D_MODEL];
    U = g*U + uu; G = g*G;
  }
  size_t idx = ((size_t)b*NCHUNK + c)*D_MODEL + d;
  Gc[idx]=G; Uc[idx]=U;
}
__global__ __launch_bounds__(512) void bscan_p2(const float* __restrict__ Gc, const float* __restrict__ Uc,
                                                float* __restrict__ binit){
  const int b = blockIdx.x, d = threadIdx.x;
  float cur = 0.f;
  for (int c=0;c<NCHUNK;++c){
    size_t idx = ((size_t)b*NCHUNK + c)*D_MODEL + d;
    binit[idx] = cur;
    cur = Gc[idx]*cur + Uc[idx];
  }
}
__global__ __launch_bounds__(512) void bscan_p3(const float* __restrict__ decay, const float* __restrict__ u,
    const float* __restrict__ binit, const float* __restrict__ a, float* __restrict__ outs){
  const int c = blockIdx.x, b = blockIdx.y, d = threadIdx.x;
  size_t base = ((size_t)b*SEQ + (size_t)c*CHUNK)*D_MODEL + d;
  float bv = binit[((size_t)b*NCHUNK + c)*D_MODEL + d];
  for (int i=0;i<CHUNK;++i){
    float g  = decay[base + (size_t)i*D_MODEL];
    float uu = u[base + (size_t)i*D_MODEL];
    bv = g*bv + uu;
    float av = a[(size_t)b*SEQ + (size_t)c*CHUNK + i];
    outs[base + (size_t)i*D_MODEL] = bv / (av + 1e-8f);
  }
}

extern "C" void kernel_launch(void* const* d_in, const int* in_sizes, int n_in,
                              void* d_out, int out_size, void* d_ws, size_t ws_size,
                              hipStream_t stream){
  const float* x     = (const float*)d_in[0];
  const float* xp    = (const float*)d_in[1];
  const float* mu    = (const float*)d_in[2];
  const float* in_w  = (const float*)d_in[3];
  const float* in_b  = (const float*)d_in[4];
  const float* out_w = (const float*)d_in[5];
  const float* out_b = (const float*)d_in[6];
  const float* ln1_g = (const float*)d_in[7];
  const float* ln1_b = (const float*)d_in[8];
  const float* tm    = (const float*)d_in[9];
  const float* sm_g  = (const float*)d_in[10];
  const float* sm_b  = (const float*)d_in[11];
  const float* wr_w  = (const float*)d_in[12];
  const float* wr_b  = (const float*)d_in[13];
  const float* wv_w  = (const float*)d_in[14];
  const float* wv_b  = (const float*)d_in[15];
  const float* sc_g  = (const float*)d_in[16];
  const float* sc_b  = (const float*)d_in[17];
  const float* ln2_g = (const float*)d_in[18];
  const float* ln2_b = (const float*)d_in[19];
  const float* w1    = (const float*)d_in[20];
  const float* b1    = (const float*)d_in[21];
  const float* w2    = (const float*)d_in[22];
  const float* b2    = (const float*)d_in[23];
  const float* ln3_g = (const float*)d_in[24];
  const float* ln3_b = (const float*)d_in[25];
  float* out = (float*)d_out;
  float* ws  = (float*)d_ws;

  const size_t N = (size_t)BATCH*SEQ*D_MODEL;   // 4,194,304
  float* S0 = ws;
  float* S1 = ws + N;
  float* S2 = ws + 2*N;
  float* S3 = ws + 3*N;
  float* S4 = ws + 4*N;
  float* EX = ws + 5*N;
  float* dm    = EX;
  float* es    = EX + (size_t)BATCH*SEQ;
  float* aarr  = EX + 2*(size_t)BATCH*SEQ;
  float* Gc    = EX + 3*(size_t)BATCH*SEQ;
  float* Uc    = Gc + (size_t)BATCH*NCHUNK*D_MODEL;
  float* binit = Uc + (size_t)BATCH*NCHUNK*D_MODEL;

  const int M = BATCH*SEQ;  // 8192

  // 1. shifted -> S0
  shift_k<<<(int)((N+255)/256), 256, 0, stream>>>(x, xp, mu, S0, (int)N);
  // 2. qkv -> S1..S3
  gemm_k<0><<<dim3(1536/64, M/64), 256, 0, stream>>>(S0, in_w, in_b, S1, M, 1536, 512);
  // 3. flash attention -> S4
  fattn_k<<<dim3(SEQ/64, NH, BATCH), 256, 0, stream>>>(S1, S4);
  // 4. attn out proj -> S1
  gemm_k<0><<<dim3(512/64, M/64), 256, 0, stream>>>(S4, out_w, out_b, S1, M, 512, 512);
  // 5. x1 = LN(shifted + attnproj) -> S2
  ln_k<1><<<M, 256, 0, stream>>>(S0, S1, ln1_g, ln1_b, S2);
  // 6. scan prep: decay -> S0, u -> S1, dm/es
  scanprep_k<<<M, 256, 0, stream>>>(S2, tm, S0, S1, dm, es);
  // 7. 'a' scan
  ascan_k<<<BATCH, 256, 0, stream>>>(dm, es, aarr);
  // 8-10. 'b' chunked scan -> outs S3
  bscan_p1<<<dim3(NCHUNK, BATCH), 512, 0, stream>>>(S0, S1, Gc, Uc);
  bscan_p2<<<BATCH, 512, 0, stream>>>(Gc, Uc, binit);
  bscan_p3<<<dim3(NCHUNK, BATCH), 512, 0, stream>>>(S0, S1, binit, aarr, S3);
  // 11. merged = LN(outs) -> S4
  ln_k<0><<<M, 256, 0, stream>>>(S3, nullptr, sm_g, sm_b, S4);
  // 12. r -> S0, v2 -> S1
  gemm_k<0><<<dim3(512/64, M/64), 256, 0, stream>>>(S4, wr_w, wr_b, S0, M, 512, 512);
  gemm_k<0><<<dim3(512/64, M/64), 256, 0, stream>>>(S4, wv_w, wv_b, S1, M, 512, 512);
  // 13. coupled = LN(sigmoid(r)*v2) -> S3
  ln_k<2><<<M, 256, 0, stream>>>(S0, S1, sc_g, sc_b, S3);
  // 14. x2 = LN(x1 + coupled) -> S0
  ln_k<1><<<M, 256, 0, stream>>>(S2, S3, ln2_g, ln2_b, S0);
  // 15. hidden = relu(x2 @ w1.T + b1) -> S1 (spans S1..S4)
  gemm_k<1><<<dim3(2048/64, M/64), 256, 0, stream>>>(S0, w1, b1, S1, M, 2048, 512);
  // 16. ffnout -> out (temp)
  gemm_k<0><<<dim3(512/64, M/64), 256, 0, stream>>>(S1, w2, b2, out, M, 512, 2048);
  // 17. final: LN(x2 + ffnout) -> out
  ln_k<1><<<M, 256, 0, stream>>>(S0, out, ln3_g, ln3_b, out);
}

// Round 3
// 409.120 us; speedup vs baseline: 16.8181x; 5.9345x over previous
//
#include <hip/hip_runtime.h>
#include <math.h>

#define D_MODEL 512
#define SEQ     2048
#define BATCH   4
#define NH      8
#define HD      64
#define CHUNK   32
#define NCHUNK  64
#define M_TOK   (BATCH*SEQ)   // 8192

typedef __attribute__((ext_vector_type(8))) short bhalf8;   // 8 bf16 = 4 VGPR
typedef __attribute__((ext_vector_type(4))) float f32x4;

__device__ __forceinline__ float sigmoidf_(float x){ return 1.f/(1.f+expf(-x)); }

__device__ __forceinline__ unsigned short f2b(float f){   // fp32 -> bf16 RNE
  unsigned u = __float_as_uint(f);
  u += 0x7FFFu + ((u>>16)&1u);
  return (unsigned short)(u>>16);
}

__device__ __forceinline__ void gll16(const void* g, void* l){
  __builtin_amdgcn_global_load_lds(
      (const __attribute__((address_space(1))) unsigned int*)g,
      (__attribute__((address_space(3))) unsigned int*)l, 16, 0, 0);
}

// ---------- block reduction ----------
__device__ __forceinline__ float block_sum(float v, float* lds){
  #pragma unroll
  for (int o=32;o>0;o>>=1) v += __shfl_xor(v,o);
  int w = threadIdx.x>>6, l = threadIdx.x&63;
  if (l==0) lds[w]=v;
  __syncthreads();
  float t=0.f; int nw = blockDim.x>>6;
  for (int i=0;i<nw;++i) t+=lds[i];
  __syncthreads();
  return t;
}

// ---------- fp32 -> bf16 weight convert (4 elems/thread) ----------
__global__ void cvt_k(const float* __restrict__ s, unsigned short* __restrict__ d, int n4){
  int i = blockIdx.x*blockDim.x + threadIdx.x;
  if (i < n4){
    float4 v = ((const float4*)s)[i];
    unsigned a=f2b(v.x), b=f2b(v.y), c=f2b(v.z), e=f2b(v.w);
    uint2 p; p.x = a | (b<<16); p.y = c | (e<<16);
    ((uint2*)d)[i] = p;
  }
}

// ---------- shift: fp32 out + bf16 out ----------
__global__ void shift2_k(const float* __restrict__ x, const float* __restrict__ xp,
                         const float* __restrict__ mu, float* __restrict__ of,
                         unsigned short* __restrict__ ob, int n4){
  int i = blockIdx.x*blockDim.x + threadIdx.x;
  if (i < n4){
    float m = mu[0];
    float4 a = ((const float4*)x)[i], p = ((const float4*)xp)[i];
    float4 r;
    r.x = m*a.x + (1.f-m)*p.x; r.y = m*a.y + (1.f-m)*p.y;
    r.z = m*a.z + (1.f-m)*p.z; r.w = m*a.w + (1.f-m)*p.w;
    ((float4*)of)[i] = r;
    unsigned A=f2b(r.x), B=f2b(r.y), C=f2b(r.z), E=f2b(r.w);
    uint2 q; q.x = A | (B<<16); q.y = C | (E<<16);
    ((uint2*)ob)[i] = q;
  }
}

// ---------- bf16 MFMA GEMM: Y[8192,Nd] = A[8192,K] @ W[Nd,K]^T + bias ----------
// 128x128 tile, BK=64, 4 waves (2x2), swizzled LDS (byte ^= (row&7)<<4),
// staged via global_load_lds with pre-swizzled global source.
template<int ACT, int OUTB>
__global__ __launch_bounds__(256) void mgemm_k(const unsigned short* __restrict__ A,
    const unsigned short* __restrict__ W, const float* __restrict__ bias,
    float* __restrict__ Yf, unsigned short* __restrict__ Yb, int Nd, int K){
  __shared__ unsigned short As[128*64];
  __shared__ unsigned short Bs[128*64];
  const int tid = threadIdx.x;
  const int w = tid>>6, lane = tid&63;
  const int l15 = lane&15, l4 = lane>>4;
  const int wr = w>>1, wc = w&1;
  const int bn = blockIdx.x, bm = blockIdx.y;

  const size_t Kb = (size_t)K*2;          // row bytes
  const int srow  = lane>>3;              // 0..7
  const int sbyte = ((lane&7)*16) ^ (srow<<4);   // pre-swizzled in-row byte
  const char* Ag = (const char*)A + (size_t)(bm*128)*Kb + sbyte;
  const char* Wg = (const char*)W + (size_t)(bn*128)*Kb + sbyte;

  f32x4 acc[4][4];
  const f32x4 z = {0.f,0.f,0.f,0.f};
  #pragma unroll
  for (int i=0;i<4;++i)
    #pragma unroll
    for (int j=0;j<4;++j) acc[i][j] = z;

  const int KT = K/64;
  for (int kt=0; kt<KT; ++kt){
    if (kt) __syncthreads();
    const size_t kOff = (size_t)kt*128;   // 64 elems * 2B
    #pragma unroll
    for (int i=0;i<4;++i){
      int c = w*4 + i;                    // chunk 0..15 -> rows c*8..c*8+8
      int r = c*8 + srow;
      gll16(Ag + (size_t)r*Kb + kOff, (char*)As + c*1024);
      gll16(Wg + (size_t)r*Kb + kOff, (char*)Bs + c*1024);
    }
    __syncthreads();

    bhalf8 af[4][2], bf_[4][2];
    #pragma unroll
    for (int fr=0; fr<4; ++fr){
      int row = wr*64 + fr*16 + l15;
      #pragma unroll
      for (int ks=0; ks<2; ++ks){
        int byo = (l4*16 + ks*64) ^ ((row&7)<<4);
        af[fr][ks] = *(const bhalf8*)((const char*)As + row*128 + byo);
      }
    }
    #pragma unroll
    for (int fc=0; fc<4; ++fc){
      int row = wc*64 + fc*16 + l15;
      #pragma unroll
      for (int ks=0; ks<2; ++ks){
        int byo = (l4*16 + ks*64) ^ ((row&7)<<4);
        bf_[fc][ks] = *(const bhalf8*)((const char*)Bs + row*128 + byo);
      }
    }
    #pragma unroll
    for (int ks=0; ks<2; ++ks)
      #pragma unroll
      for (int fr=0; fr<4; ++fr)
        #pragma unroll
        for (int fc=0; fc<4; ++fc)
          acc[fr][fc] = __builtin_amdgcn_mfma_f32_16x16x32_bf16(af[fr][ks], bf_[fc][ks], acc[fr][fc], 0, 0, 0);
  }

  // epilogue: C[row][col], col=lane&15, row=(lane>>4)*4+reg
  const int rowBase = bm*128 + wr*64;
  const int colBase = bn*128 + wc*64;
  #pragma unroll
  for (int fc=0; fc<4; ++fc){
    int col = colBase + fc*16 + l15;
    float bv = bias[col];
    #pragma unroll
    for (int fr=0; fr<4; ++fr){
      #pragma unroll
      for (int j=0; j<4; ++j){
        int row = rowBase + fr*16 + l4*4 + j;
        float v = acc[fr][fc][j] + bv;
        if (ACT) v = fmaxf(v, 0.f);
        if (OUTB) Yb[(size_t)row*Nd + col] = f2b(v);
        else      Yf[(size_t)row*Nd + col] = v;
      }
    }
  }
}

// ---------- bf16 MFMA flash attention ----------
// block = (qt, h, b): 64 q-rows, 4 waves each own 16 rows. kv tiles of 64.
// qkv: [8192, 1536] bf16 (Q|K|V). ao: [8192, 512] bf16.
__global__ __launch_bounds__(256) void fattn_k(const unsigned short* __restrict__ qkv,
                                               unsigned short* __restrict__ ao){
  __shared__ unsigned short Ks[64*64];
  __shared__ unsigned short Vt[64*64];
  __shared__ unsigned short Ps[64*64];
  const int qt = blockIdx.x, h = blockIdx.y, b = blockIdx.z;
  const int tid = threadIdx.x, w = tid>>6, lane = tid&63;
  const int l15 = lane&15, l4 = lane>>4;
  const size_t rowB = 3072;                 // 1536 shorts
  const char* base = (const char*)qkv + (size_t)b*SEQ*rowB;

  // Q fragments (A-operand): row = qt*64 + w*16 + l15, k = l4*8 + ks*32
  bhalf8 qf[2];
  {
    const char* qrow = base + (size_t)(qt*64 + w*16 + l15)*rowB + h*128;
    qf[0] = *(const bhalf8*)(qrow + l4*16);
    qf[1] = *(const bhalf8*)(qrow + l4*16 + 64);
  }

  const f32x4 z = {0.f,0.f,0.f,0.f};
  f32x4 oa[4]; 
  #pragma unroll
  for (int i=0;i<4;++i) oa[i] = z;
  float mj[4] = {-INFINITY,-INFINITY,-INFINITY,-INFINITY};
  float lj[4] = {0.f,0.f,0.f,0.f};

  const int srow  = lane>>3;
  const int sbyte = ((lane&7)*16) ^ (srow<<4);

  for (int kt = 0; kt < SEQ/64; ++kt){
    if (kt) __syncthreads();
    // stage K tile via global_load_lds (pre-swizzled source)
    #pragma unroll
    for (int i=0;i<2;++i){
      int c = w*2 + i;                      // 0..7 -> rows c*8..+8
      int r = c*8 + srow;
      gll16(base + (size_t)(kt*64 + r)*rowB + 1024 + h*128 + sbyte,
            (char*)Ks + c*1024);
    }
    // stage V transposed (reg-staged, swizzled writes)
    {
      int vr = tid>>2, cb = tid&3;
      const char* vrow = base + (size_t)(kt*64 + vr)*rowB + 2048 + h*128 + cb*32;
      bhalf8 v0 = *(const bhalf8*)(vrow);
      bhalf8 v1 = *(const bhalf8*)(vrow + 16);
      #pragma unroll
      for (int e=0;e<8;++e){
        int d0 = cb*16 + e, d1 = cb*16 + 8 + e;
        Vt[d0*64 + (vr ^ ((d0&7)<<3))] = (unsigned short)v0[e];
        Vt[d1*64 + (vr ^ ((d1&7)<<3))] = (unsigned short)v1[e];
      }
    }
    __syncthreads();

    // S = Q K^T
    f32x4 s[4];
    #pragma unroll
    for (int i=0;i<4;++i) s[i] = z;
    bhalf8 kf[4][2];
    #pragma unroll
    for (int fc=0; fc<4; ++fc){
      int kr = fc*16 + l15;
      #pragma unroll
      for (int ks=0; ks<2; ++ks){
        int byo = (l4*16 + ks*64) ^ ((kr&7)<<4);
        kf[fc][ks] = *(const bhalf8*)((const char*)Ks + kr*128 + byo);
      }
    }
    #pragma unroll
    for (int ks=0; ks<2; ++ks)
      #pragma unroll
      for (int fc=0; fc<4; ++fc)
        s[fc] = __builtin_amdgcn_mfma_f32_16x16x32_bf16(qf[ks], kf[fc][ks], s[fc], 0, 0, 0);
    #pragma unroll
    for (int fc=0; fc<4; ++fc) s[fc] *= 0.125f;

    // online softmax (rows j=0..3, row = w*16 + l4*4 + j)
    float pj[4][4];
    #pragma unroll
    for (int j=0; j<4; ++j){
      float mr = fmaxf(fmaxf(s[0][j],s[1][j]), fmaxf(s[2][j],s[3][j]));
      mr = fmaxf(mr, __shfl_xor(mr,1));
      mr = fmaxf(mr, __shfl_xor(mr,2));
      mr = fmaxf(mr, __shfl_xor(mr,4));
      mr = fmaxf(mr, __shfl_xor(mr,8));
      float mn = fmaxf(mj[j], mr);
      float sc = __expf(mj[j]-mn);
      float rs = 0.f;
      #pragma unroll
      for (int fc=0; fc<4; ++fc){ float p = __expf(s[fc][j]-mn); pj[fc][j]=p; rs += p; }
      rs += __shfl_xor(rs,1); rs += __shfl_xor(rs,2);
      rs += __shfl_xor(rs,4); rs += __shfl_xor(rs,8);
      lj[j] = lj[j]*sc + rs;
      mj[j] = mn;
      #pragma unroll
      for (int fc=0; fc<4; ++fc) oa[fc][j] *= sc;
    }

    // write P to wave-private LDS rows (no barrier needed)
    #pragma unroll
    for (int fc=0; fc<4; ++fc){
      int c = fc*16 + l15;
      #pragma unroll
      for (int j=0; j<4; ++j){
        int qr = w*16 + l4*4 + j;
        Ps[qr*64 + (c ^ ((qr&7)<<3))] = f2b(pj[fc][j]);
      }
    }

    // O += P V
    bhalf8 pf[2], vf[4][2];
    {
      int qr = w*16 + l15;
      #pragma unroll
      for (int ks=0; ks<2; ++ks){
        int byo = (l4*16 + ks*64) ^ ((qr&7)<<4);
        pf[ks] = *(const bhalf8*)((const char*)Ps + qr*128 + byo);
      }
    }
    #pragma unroll
    for (int fc=0; fc<4; ++fc){
      int d = fc*16 + l15;
      #pragma unroll
      for (int ks=0; ks<2; ++ks){
        int byo = (l4*16 + ks*64) ^ ((d&7)<<4);
        vf[fc][ks] = *(const bhalf8*)((const char*)Vt + d*128 + byo);
      }
    }
    #pragma unroll
    for (int ks=0; ks<2; ++ks)
      #pragma unroll
      for (int fc=0; fc<4; ++fc)
        oa[fc] = __builtin_amdgcn_mfma_f32_16x16x32_bf16(pf[ks], vf[fc][ks], oa[fc], 0, 0, 0);
  }

  // epilogue
  #pragma unroll
  for (int j=0; j<4; ++j){
    float inv = 1.f/lj[j];
    int row = qt*64 + w*16 + l4*4 + j;
    #pragma unroll
    for (int fc=0; fc<4; ++fc){
      int col = h*64 + fc*16 + l15;
      ao[((size_t)(b*SEQ + row))*D_MODEL + col] = f2b(oa[fc][j]*inv);
    }
  }
}

// ---------- LayerNorm over D=512; MODE 0: A, 1: A+B, 2: sigmoid(A)*B ----------
template<int MODE, int WF32, int WB16>
__global__ __launch_bounds__(256) void ln_k(const float* A, const float* Bp,
    const float* g, const float* be, float* outf, unsigned short* outb){
  __shared__ float lds[4];
  const size_t off = (size_t)blockIdx.x * D_MODEL;
  const int tid = threadIdx.x;
  float a0 = A[off+tid], a1 = A[off+tid+256];
  if (MODE==1){ a0 += Bp[off+tid]; a1 += Bp[off+tid+256]; }
  if (MODE==2){ a0 = sigmoidf_(a0)*Bp[off+tid]; a1 = sigmoidf_(a1)*Bp[off+tid+256]; }
  float mean = block_sum(a0+a1, lds) * (1.f/512.f);
  float d0=a0-mean, d1=a1-mean;
  float var = block_sum(d0*d0+d1*d1, lds) * (1.f/512.f);
  float rstd = rsqrtf(var + 1e-5f);
  float r0 = d0*rstd*g[tid]     + be[tid];
  float r1 = d1*rstd*g[tid+256] + be[tid+256];
  if (WF32){ outf[off+tid] = r0; outf[off+tid+256] = r1; }
  if (WB16){ outb[off+tid] = f2b(r0); outb[off+tid+256] = f2b(r1); }
}

// ---------- scan prep ----------
__global__ __launch_bounds__(256) void scanprep_k(const float* __restrict__ x1, const float* __restrict__ tm,
    float* __restrict__ decay, float* __restrict__ u, float* __restrict__ dm, float* __restrict__ es){
  __shared__ float lds[4];
  const size_t row = blockIdx.x;
  const size_t off = row * D_MODEL;
  const int tid = threadIdx.x;
  float x0 = x1[off+tid], xv1 = x1[off+tid+256];
  float d0 = sigmoidf_(x0*tm[tid]), d1 = sigmoidf_(xv1*tm[tid+256]);
  float e0 = expf(x0), e1 = expf(xv1);
  decay[off+tid]=d0; decay[off+tid+256]=d1;
  u[off+tid]=e0*x0;  u[off+tid+256]=e1*xv1;
  float dsum = block_sum(d0+d1, lds);
  float esum = block_sum(e0+e1, lds);
  if (tid==0){ dm[row]=dsum*(1.f/512.f); es[row]=esum; }
}

// ---------- scalar 'a' scan per batch ----------
__global__ __launch_bounds__(256) void ascan_k(const float* __restrict__ dm, const float* __restrict__ es,
                                               float* __restrict__ a_out){
  __shared__ float sG[256], sU[256];
  const int b = blockIdx.x, tid = threadIdx.x;
  const float* dmb = dm + (size_t)b*SEQ;
  const float* esb = es + (size_t)b*SEQ;
  const int t0 = tid*8;
  float gi[8], ui[8];
  #pragma unroll
  for (int i=0;i<8;++i){ gi[i]=dmb[t0+i]; ui[i]=esb[t0+i]; }
  float G=1.f, U=0.f;
  #pragma unroll
  for (int i=0;i<8;++i){ U = gi[i]*U + ui[i]; G *= gi[i]; }
  sG[tid]=G; sU[tid]=U;
  __syncthreads();
  for (int off=1; off<256; off<<=1){
    float pg=1.f, pu=0.f;
    bool act = tid >= off;
    if (act){ pg = sG[tid-off]; pu = sU[tid-off]; }
    __syncthreads();
    if (act){ sU[tid] = sG[tid]*pu + sU[tid]; sG[tid] = sG[tid]*pg; }
    __syncthreads();
  }
  float a = (tid==0) ? 0.f : sU[tid-1];
  #pragma unroll
  for (int i=0;i<8;++i){ a = gi[i]*a + ui[i]; a_out[(size_t)b*SEQ + t0 + i] = a; }
}

// ---------- b scan: chunked ----------
__global__ __launch_bounds__(512) void bscan_p1(const float* __restrict__ decay, const float* __restrict__ u,
    float* __restrict__ Gc, float* __restrict__ Uc){
  const int c = blockIdx.x, b = blockIdx.y, d = threadIdx.x;
  size_t base = ((size_t)b*SEQ + (size_t)c*CHUNK)*D_MODEL + d;
  float G=1.f, U=0.f;
  for (int i=0;i<CHUNK;++i){
    float g  = decay[base + (size_t)i*D_MODEL];
    float uu = u[base + (size_t)i*D_MODEL];
    U = g*U + uu; G = g*G;
  }
  size_t idx = ((size_t)b*NCHUNK + c)*D_MODEL + d;
  Gc[idx]=G; Uc[idx]=U;
}
__global__ __launch_bounds__(512) void bscan_p2(const float* __restrict__ Gc, const float* __restrict__ Uc,
                                                float* __restrict__ binit){
  const int b = blockIdx.x, d = threadIdx.x;
  float cur = 0.f;
  for (int c=0;c<NCHUNK;++c){
    size_t idx = ((size_t)b*NCHUNK + c)*D_MODEL + d;
    binit[idx] = cur;
    cur = Gc[idx]*cur + Uc[idx];
  }
}
// NOTE: u and outs may alias (in-place); no __restrict__ on them.
__global__ __launch_bounds__(512) void bscan_p3(const float* __restrict__ decay, const float* u,
    const float* __restrict__ binit, const float* __restrict__ a, float* outs){
  const int c = blockIdx.x, b = blockIdx.y, d = threadIdx.x;
  size_t base = ((size_t)b*SEQ + (size_t)c*CHUNK)*D_MODEL + d;
  float bv = binit[((size_t)b*NCHUNK + c)*D_MODEL + d];
  for (int i=0;i<CHUNK;++i){
    float g  = decay[base + (size_t)i*D_MODEL];
    float uu = u[base + (size_t)i*D_MODEL];
    bv = g*bv + uu;
    float av = a[(size_t)b*SEQ + (size_t)c*CHUNK + i];
    outs[base + (size_t)i*D_MODEL] = bv / (av + 1e-8f);
  }
}

extern "C" void kernel_launch(void* const* d_in, const int* in_sizes, int n_in,
                              void* d_out, int out_size, void* d_ws, size_t ws_size,
                              hipStream_t stream){
  const float* x     = (const float*)d_in[0];
  const float* xp    = (const float*)d_in[1];
  const float* mu    = (const float*)d_in[2];
  const float* in_w  = (const float*)d_in[3];
  const float* in_b  = (const float*)d_in[4];
  const float* out_w = (const float*)d_in[5];
  const float* out_b = (const float*)d_in[6];
  const float* ln1_g = (const float*)d_in[7];
  const float* ln1_b = (const float*)d_in[8];
  const float* tm    = (const float*)d_in[9];
  const float* sm_g  = (const float*)d_in[10];
  const float* sm_b  = (const float*)d_in[11];
  const float* wr_w  = (const float*)d_in[12];
  const float* wr_b  = (const float*)d_in[13];
  const float* wv_w  = (const float*)d_in[14];
  const float* wv_b  = (const float*)d_in[15];
  const float* sc_g  = (const float*)d_in[16];
  const float* sc_b  = (const float*)d_in[17];
  const float* ln2_g = (const float*)d_in[18];
  const float* ln2_b = (const float*)d_in[19];
  const float* w1    = (const float*)d_in[20];
  const float* b1    = (const float*)d_in[21];
  const float* w2    = (const float*)d_in[22];
  const float* b2    = (const float*)d_in[23];
  const float* ln3_g = (const float*)d_in[24];
  const float* ln3_b = (const float*)d_in[25];
  float* out = (float*)d_out;
  float* ws  = (float*)d_ws;

  const size_t N = (size_t)M_TOK*D_MODEL;   // 4,194,304
  float* S0f = ws;
  float* S1f = ws + N;
  float* S2f = ws + 2*N;
  float* EX  = ws + 3*N;
  float* dm    = EX;
  float* es    = EX + 8192;
  float* aarr  = EX + 16384;
  float* Gc    = EX + 24576;
  float* Uc    = Gc + 131072;
  float* binit = Uc + 131072;

  unsigned short* SB = (unsigned short*)(ws + 3*N + N/4);
  unsigned short* Wq = SB;                       // 786432
  unsigned short* Wo = Wq + 786432;              // 262144
  unsigned short* Wr = Wo + 262144;
  unsigned short* Wv = Wr + 262144;
  unsigned short* W1 = Wv + 262144;              // 1048576
  unsigned short* W2 = W1 + 1048576;
  unsigned short* Xb = W2 + 1048576;             // 4M  (shifted bf16, later x2 bf16)
  unsigned short* Mb = Xb + N;                   // 4M  (merged bf16)
  unsigned short* U  = Mb + N;                   // 16M region
  unsigned short* Qb  = U;                       // 12M (qkv bf16)
  unsigned short* AOb = U + 12*1024*1024;        // 4M  (attn out bf16)
  unsigned short* Hb  = U;                       // 16M (ffn hidden bf16, reuses U)

  // weight conversions (independent)
  cvt_k<<<768, 256, 0, stream>>>(in_w,  Wq, 196608);
  cvt_k<<<256, 256, 0, stream>>>(out_w, Wo, 65536);
  cvt_k<<<256, 256, 0, stream>>>(wr_w,  Wr, 65536);
  cvt_k<<<256, 256, 0, stream>>>(wv_w,  Wv, 65536);
  cvt_k<<<1024,256, 0, stream>>>(w1,    W1, 262144);
  cvt_k<<<1024,256, 0, stream>>>(w2,    W2, 262144);
  // 1. shifted -> S0f (fp32) + Xb (bf16)
  shift2_k<<<4096, 256, 0, stream>>>(x, xp, mu, S0f, Xb, (int)(N/4));
  // 2. qkv (bf16) -> Qb
  mgemm_k<0,1><<<dim3(12,64), 256, 0, stream>>>(Xb, Wq, in_b, nullptr, Qb, 1536, 512);
  // 3. flash attention -> AOb
  fattn_k<<<dim3(SEQ/64, NH, BATCH), 256, 0, stream>>>(Qb, AOb);
  // 4. out-proj -> S1f (fp32)
  mgemm_k<0,0><<<dim3(4,64), 256, 0, stream>>>(AOb, Wo, out_b, S1f, nullptr, 512, 512);
  // 5. x1 = LN(shifted + proj) -> S2f
  ln_k<1,1,0><<<M_TOK, 256, 0, stream>>>(S0f, S1f, ln1_g, ln1_b, S2f, nullptr);
  // 6. scan prep: decay->S0f, u->S1f
  scanprep_k<<<M_TOK, 256, 0, stream>>>(S2f, tm, S0f, S1f, dm, es);
  // 7. 'a' scan
  ascan_k<<<BATCH, 256, 0, stream>>>(dm, es, aarr);
  // 8-10. 'b' scan -> outs (in-place over u = S1f)
  bscan_p1<<<dim3(NCHUNK, BATCH), 512, 0, stream>>>(S0f, S1f, Gc, Uc);
  bscan_p2<<<BATCH, 512, 0, stream>>>(Gc, Uc, binit);
  bscan_p3<<<dim3(NCHUNK, BATCH), 512, 0, stream>>>(S0f, S1f, binit, aarr, S1f);
  // 11. merged = LN(outs) -> Mb (bf16)
  ln_k<0,0,1><<<M_TOK, 256, 0, stream>>>(S1f, nullptr, sm_g, sm_b, nullptr, Mb);
  // 12. r -> S0f, v -> S1f
  mgemm_k<0,0><<<dim3(4,64), 256, 0, stream>>>(Mb, Wr, wr_b, S0f, nullptr, 512, 512);
  mgemm_k<0,0><<<dim3(4,64), 256, 0, stream>>>(Mb, Wv, wv_b, S1f, nullptr, 512, 512);
  // 13. coupled = LN(sigmoid(r)*v) -> S1f (in-place over v)
  ln_k<2,1,0><<<M_TOK, 256, 0, stream>>>(S0f, S1f, sc_g, sc_b, S1f, nullptr);
  // 14. x2 = LN(x1 + coupled) -> S0f (fp32) + Xb (bf16)
  ln_k<1,1,1><<<M_TOK, 256, 0, stream>>>(S2f, S1f, ln2_g, ln2_b, S0f, Xb);
  // 15. hidden = relu(x2 @ w1.T + b1) -> Hb (bf16)
  mgemm_k<1,1><<<dim3(16,64), 256, 0, stream>>>(Xb, W1, b1, nullptr, Hb, 2048, 512);
  // 16. ffnout -> S1f (fp32)
  mgemm_k<0,0><<<dim3(4,64), 256, 0, stream>>>(Hb, W2, b2, S1f, nullptr, 512, 2048);
  // 17. out = LN(x2 + ffnout)
  ln_k<1,1,0><<<M_TOK, 256, 0, stream>>>(S0f, S1f, ln3_g, ln3_b, out, nullptr);
}

// Round 4
// 389.666 us; speedup vs baseline: 17.6577x; 1.0499x over previous
//
#include <hip/hip_runtime.h>
#include <math.h>

#define D_MODEL 512
#define SEQ     2048
#define BATCH   4
#define NH      8
#define HD      64
#define CHUNK   32
#define NCHUNK  64
#define M_TOK   (BATCH*SEQ)   // 8192

typedef __attribute__((ext_vector_type(8))) short bhalf8;   // 8 bf16 = 4 VGPR
typedef __attribute__((ext_vector_type(4))) float f32x4;

__device__ __forceinline__ float sigmoidf_(float x){ return 1.f/(1.f+expf(-x)); }

__device__ __forceinline__ unsigned short f2b(float f){   // fp32 -> bf16 RNE
  unsigned u = __float_as_uint(f);
  u += 0x7FFFu + ((u>>16)&1u);
  return (unsigned short)(u>>16);
}

__device__ __forceinline__ void gll16(const void* g, void* l){
  __builtin_amdgcn_global_load_lds(
      (const __attribute__((address_space(1))) unsigned int*)g,
      (__attribute__((address_space(3))) unsigned int*)l, 16, 0, 0);
}

// ---------- block reduction ----------
__device__ __forceinline__ float block_sum(float v, float* lds){
  #pragma unroll
  for (int o=32;o>0;o>>=1) v += __shfl_xor(v,o);
  int w = threadIdx.x>>6, l = threadIdx.x&63;
  if (l==0) lds[w]=v;
  __syncthreads();
  float t=0.f; int nw = blockDim.x>>6;
  for (int i=0;i<nw;++i) t+=lds[i];
  __syncthreads();
  return t;
}

// ---------- fp32 -> bf16 weight convert ----------
__global__ void cvt_k(const float* __restrict__ s, unsigned short* __restrict__ d, int n4){
  int i = blockIdx.x*blockDim.x + threadIdx.x;
  if (i < n4){
    float4 v = ((const float4*)s)[i];
    unsigned a=f2b(v.x), b=f2b(v.y), c=f2b(v.z), e=f2b(v.w);
    uint2 p; p.x = a | (b<<16); p.y = c | (e<<16);
    ((uint2*)d)[i] = p;
  }
}

// ---------- shift: fp32 out + bf16 out ----------
__global__ void shift2_k(const float* __restrict__ x, const float* __restrict__ xp,
                         const float* __restrict__ mu, float* __restrict__ of,
                         unsigned short* __restrict__ ob, int n4){
  int i = blockIdx.x*blockDim.x + threadIdx.x;
  if (i < n4){
    float m = mu[0];
    float4 a = ((const float4*)x)[i], p = ((const float4*)xp)[i];
    float4 r;
    r.x = m*a.x + (1.f-m)*p.x; r.y = m*a.y + (1.f-m)*p.y;
    r.z = m*a.z + (1.f-m)*p.z; r.w = m*a.w + (1.f-m)*p.w;
    ((float4*)of)[i] = r;
    unsigned A=f2b(r.x), B=f2b(r.y), C=f2b(r.z), E=f2b(r.w);
    uint2 q; q.x = A | (B<<16); q.y = C | (E<<16);
    ((uint2*)ob)[i] = q;
  }
}

// ---------- bf16 MFMA GEMM (unchanged from R3, verified) ----------
template<int ACT, int OUTB>
__global__ __launch_bounds__(256) void mgemm_k(const unsigned short* __restrict__ A,
    const unsigned short* __restrict__ W, const float* __restrict__ bias,
    float* __restrict__ Yf, unsigned short* __restrict__ Yb, int Nd, int K){
  __shared__ unsigned short As[128*64];
  __shared__ unsigned short Bs[128*64];
  const int tid = threadIdx.x;
  const int w = tid>>6, lane = tid&63;
  const int l15 = lane&15, l4 = lane>>4;
  const int wr = w>>1, wc = w&1;
  const int bn = blockIdx.x, bm = blockIdx.y;

  const size_t Kb = (size_t)K*2;
  const int srow  = lane>>3;
  const int sbyte = ((lane&7)*16) ^ (srow<<4);
  const char* Ag = (const char*)A + (size_t)(bm*128)*Kb + sbyte;
  const char* Wg = (const char*)W + (size_t)(bn*128)*Kb + sbyte;

  f32x4 acc[4][4];
  const f32x4 z = {0.f,0.f,0.f,0.f};
  #pragma unroll
  for (int i=0;i<4;++i)
    #pragma unroll
    for (int j=0;j<4;++j) acc[i][j] = z;

  const int KT = K/64;
  for (int kt=0; kt<KT; ++kt){
    if (kt) __syncthreads();
    const size_t kOff = (size_t)kt*128;
    #pragma unroll
    for (int i=0;i<4;++i){
      int c = w*4 + i;
      int r = c*8 + srow;
      gll16(Ag + (size_t)r*Kb + kOff, (char*)As + c*1024);
      gll16(Wg + (size_t)r*Kb + kOff, (char*)Bs + c*1024);
    }
    __syncthreads();

    bhalf8 af[4][2], bf_[4][2];
    #pragma unroll
    for (int fr=0; fr<4; ++fr){
      int row = wr*64 + fr*16 + l15;
      #pragma unroll
      for (int ks=0; ks<2; ++ks){
        int byo = (l4*16 + ks*64) ^ ((row&7)<<4);
        af[fr][ks] = *(const bhalf8*)((const char*)As + row*128 + byo);
      }
    }
    #pragma unroll
    for (int fc=0; fc<4; ++fc){
      int row = wc*64 + fc*16 + l15;
      #pragma unroll
      for (int ks=0; ks<2; ++ks){
        int byo = (l4*16 + ks*64) ^ ((row&7)<<4);
        bf_[fc][ks] = *(const bhalf8*)((const char*)Bs + row*128 + byo);
      }
    }
    #pragma unroll
    for (int ks=0; ks<2; ++ks)
      #pragma unroll
      for (int fr=0; fr<4; ++fr)
        #pragma unroll
        for (int fc=0; fc<4; ++fc)
          acc[fr][fc] = __builtin_amdgcn_mfma_f32_16x16x32_bf16(af[fr][ks], bf_[fc][ks], acc[fr][fc], 0, 0, 0);
  }

  const int rowBase = bm*128 + wr*64;
  const int colBase = bn*128 + wc*64;
  #pragma unroll
  for (int fc=0; fc<4; ++fc){
    int col = colBase + fc*16 + l15;
    float bv = bias[col];
    #pragma unroll
    for (int fr=0; fr<4; ++fr){
      #pragma unroll
      for (int j=0; j<4; ++j){
        int row = rowBase + fr*16 + l4*4 + j;
        float v = acc[fr][fc][j] + bv;
        if (ACT) v = fmaxf(v, 0.f);
        if (OUTB) Yb[(size_t)row*Nd + col] = f2b(v);
        else      Yf[(size_t)row*Nd + col] = v;
      }
    }
  }
}

// ---------- bf16 MFMA flash attention, swapped-QK, QBLK=128, dbuf ----------
// block = (qt, h, b): 128 q-rows, 4 waves x 32 rows (2 subtiles of 16).
// S^T via mfma(K,Q): lane holds S[kv=fc*16+l4*4+j][q=l15] -> row-softmax in-lane.
__global__ __launch_bounds__(256) void fattn_k(const unsigned short* __restrict__ qkv,
                                               unsigned short* __restrict__ ao){
  __shared__ unsigned short Ks[2][64*64];
  __shared__ unsigned short Vt[2][64*64];
  __shared__ unsigned short Ps[128*64];
  const int qt = blockIdx.x, h = blockIdx.y, b = blockIdx.z;
  const int tid = threadIdx.x, w = tid>>6, lane = tid&63;
  const int l15 = lane&15, l4 = lane>>4;
  const size_t rowB = 3072;                 // 1536 bf16 per token row
  const char* base = (const char*)qkv + (size_t)b*SEQ*rowB;
  const char* Kg = base + 1024 + h*128;     // K block (bytes)
  const char* Vg = base + 2048 + h*128;     // V block

  // Q fragments (B-operand): qf[t][ks], q = qt*128 + w*32 + t*16 + l15
  bhalf8 qf[2][2];
  #pragma unroll
  for (int t=0;t<2;++t){
    const char* qrow = base + (size_t)(qt*128 + w*32 + t*16 + l15)*rowB + h*128;
    qf[t][0] = *(const bhalf8*)(qrow + l4*16);
    qf[t][1] = *(const bhalf8*)(qrow + l4*16 + 64);
  }

  const f32x4 z = {0.f,0.f,0.f,0.f};
  f32x4 oa[2][4];
  #pragma unroll
  for (int t=0;t<2;++t)
    #pragma unroll
    for (int i=0;i<4;++i) oa[t][i] = z;
  float mj[2] = {-INFINITY,-INFINITY};
  float lj[2] = {0.f,0.f};

  // K staging (gll16, pre-swizzled source)
  const int srow  = lane>>3;
  const int sbyte = ((lane&7)*16) ^ (srow<<4);
  // V transpose staging: thread -> (d, kv-block)
  const int vd  = tid & 63;
  const int vkb = tid >> 6;     // 0..3, 16 kv rows each

  unsigned vload[16];
  // prologue: stage tile 0
  #pragma unroll
  for (int i=0;i<4;++i){
    int c = w*4 + i, r = c*8 + srow;
    gll16(Kg + (size_t)r*rowB + sbyte, (char*)Ks[0] + c*1024);
  }
  #pragma unroll
  for (int i=0;i<16;++i)
    vload[i] = *(const unsigned short*)(Vg + (size_t)(vkb*16 + i)*rowB + vd*2);

  int cur = 0;
  for (int kt=0; kt<SEQ/64; ++kt){
    // write Vt[cur] from regs: 4 clean b64 swizzled writes
    #pragma unroll
    for (int p=0;p<4;++p){
      unsigned lo = (vload[p*4+0]&0xFFFFu) | (vload[p*4+1]<<16);
      unsigned hi = (vload[p*4+2]&0xFFFFu) | (vload[p*4+3]<<16);
      uint2 pk; pk.x = lo; pk.y = hi;
      int byo = (vkb*32 + p*8) ^ ((vd&7)<<4);
      *(uint2*)((char*)Vt[cur] + vd*128 + byo) = pk;
    }
    __syncthreads();   // Ks[cur] gll16 drained + Vt[cur] visible

    if (kt+1 < SEQ/64){
      #pragma unroll
      for (int i=0;i<4;++i){
        int c = w*4 + i, r = c*8 + srow;
        gll16(Kg + (size_t)((kt+1)*64 + r)*rowB + sbyte, (char*)Ks[cur^1] + c*1024);
      }
      #pragma unroll
      for (int i=0;i<16;++i)
        vload[i] = *(const unsigned short*)(Vg + (size_t)((kt+1)*64 + vkb*16 + i)*rowB + vd*2);
    }

    // ---- compute from buffers [cur] ----
    // K fragments (A-operand): lane holds K[kv=fc*16+l15][hd=l4*8+e]
    bhalf8 kf[4][2];
    #pragma unroll
    for (int fc=0; fc<4; ++fc){
      int kr = fc*16 + l15;
      #pragma unroll
      for (int ks=0; ks<2; ++ks){
        int byo = (l4*16 + ks*64) ^ ((kr&7)<<4);
        kf[fc][ks] = *(const bhalf8*)((const char*)Ks[cur] + kr*128 + byo);
      }
    }
    // S^T = K Q^T : s[t][fc], lane holds S[kv=fc*16+l4*4+j][q=l15]
    f32x4 s[2][4];
    #pragma unroll
    for (int t=0;t<2;++t)
      #pragma unroll
      for (int i=0;i<4;++i) s[t][i] = z;
    #pragma unroll
    for (int ks=0; ks<2; ++ks)
      #pragma unroll
      for (int t=0; t<2; ++t)
        #pragma unroll
        for (int fc=0; fc<4; ++fc)
          s[t][fc] = __builtin_amdgcn_mfma_f32_16x16x32_bf16(kf[fc][ks], qf[t][ks], s[t][fc], 0, 0, 0);

    // softmax per subtile (row q = l15, 16 kv per lane, reduce over l4 groups)
    #pragma unroll
    for (int t=0; t<2; ++t){
      float rm = s[t][0][0];
      #pragma unroll
      for (int fc=0; fc<4; ++fc)
        #pragma unroll
        for (int j=0; j<4; ++j) rm = fmaxf(rm, s[t][fc][j]);
      rm = fmaxf(rm, __shfl_xor(rm,16));
      rm = fmaxf(rm, __shfl_xor(rm,32));
      float mn = fmaxf(mj[t], 0.125f*rm);
      float sc = __expf(mj[t]-mn);
      float p[4][4];
      float rs = 0.f;
      #pragma unroll
      for (int fc=0; fc<4; ++fc)
        #pragma unroll
        for (int j=0; j<4; ++j){
          float e = __expf(fmaf(0.125f, s[t][fc][j], -mn));
          p[fc][j] = e; rs += e;
        }
      rs += __shfl_xor(rs,16);
      rs += __shfl_xor(rs,32);
      lj[t] = lj[t]*sc + rs;
      mj[t] = mn;
      // rescale O (O rows live at q = l4*4+j -> broadcast sc from lane q)
      float scj0 = __shfl(sc, l4*4+0), scj1 = __shfl(sc, l4*4+1);
      float scj2 = __shfl(sc, l4*4+2), scj3 = __shfl(sc, l4*4+3);
      #pragma unroll
      for (int fc=0; fc<4; ++fc){
        oa[t][fc][0] *= scj0; oa[t][fc][1] *= scj1;
        oa[t][fc][2] *= scj2; oa[t][fc][3] *= scj3;
      }
      // pack P -> 4 clean b64 swizzled writes (wave-private rows)
      int qrow = w*32 + t*16 + l15;
      #pragma unroll
      for (int fc=0; fc<4; ++fc){
        unsigned lo = (unsigned)f2b(p[fc][0]) | ((unsigned)f2b(p[fc][1])<<16);
        unsigned hi = (unsigned)f2b(p[fc][2]) | ((unsigned)f2b(p[fc][3])<<16);
        uint2 pk; pk.x = lo; pk.y = hi;
        int byo = (fc*32 + l4*8) ^ ((l15&7)<<4);
        *(uint2*)((char*)Ps + qrow*128 + byo) = pk;
      }
    }

    // V fragments (B-operand): lane holds V[kv=l4*8+e][d=fc*16+l15]
    bhalf8 vf[4][2];
    #pragma unroll
    for (int fc=0; fc<4; ++fc){
      int d = fc*16 + l15;
      #pragma unroll
      for (int ks=0; ks<2; ++ks){
        int byo = (ks*64 + l4*16) ^ ((d&7)<<4);
        vf[fc][ks] = *(const bhalf8*)((const char*)Vt[cur] + d*128 + byo);
      }
    }
    // O += P V  (A = P: lane holds P[q=l15][kv=ks*32+l4*8+e])
    #pragma unroll
    for (int t=0; t<2; ++t){
      int qrow = w*32 + t*16 + l15;
      bhalf8 pf[2];
      #pragma unroll
      for (int ks=0; ks<2; ++ks){
        int byo = (ks*64 + l4*16) ^ ((l15&7)<<4);
        pf[ks] = *(const bhalf8*)((const char*)Ps + qrow*128 + byo);
      }
      #pragma unroll
      for (int ks=0; ks<2; ++ks)
        #pragma unroll
        for (int fc=0; fc<4; ++fc)
          oa[t][fc] = __builtin_amdgcn_mfma_f32_16x16x32_bf16(pf[ks], vf[fc][ks], oa[t][fc], 0, 0, 0);
    }
    cur ^= 1;
  }

  // epilogue: O[q=l4*4+j][d=fc*16+l15], 1/l broadcast from lane q
  #pragma unroll
  for (int t=0; t<2; ++t){
    float linv = 1.f/lj[t];
    float li0 = __shfl(linv, l4*4+0), li1 = __shfl(linv, l4*4+1);
    float li2 = __shfl(linv, l4*4+2), li3 = __shfl(linv, l4*4+3);
    #pragma unroll
    for (int fc=0; fc<4; ++fc){
      int col = h*64 + fc*16 + l15;
      size_t r0 = (size_t)(b*SEQ + qt*128 + w*32 + t*16 + l4*4);
      ao[(r0+0)*D_MODEL + col] = f2b(oa[t][fc][0]*li0);
      ao[(r0+1)*D_MODEL + col] = f2b(oa[t][fc][1]*li1);
      ao[(r0+2)*D_MODEL + col] = f2b(oa[t][fc][2]*li2);
      ao[(r0+3)*D_MODEL + col] = f2b(oa[t][fc][3]*li3);
    }
  }
}

// ---------- LayerNorm over D=512; MODE 0: A, 1: A+B, 2: sigmoid(A)*B ----------
template<int MODE, int WF32, int WB16>
__global__ __launch_bounds__(256) void ln_k(const float* A, const float* Bp,
    const float* g, const float* be, float* outf, unsigned short* outb){
  __shared__ float lds[4];
  const size_t off = (size_t)blockIdx.x * D_MODEL;
  const int tid = threadIdx.x;
  float a0 = A[off+tid], a1 = A[off+tid+256];
  if (MODE==1){ a0 += Bp[off+tid]; a1 += Bp[off+tid+256]; }
  if (MODE==2){ a0 = sigmoidf_(a0)*Bp[off+tid]; a1 = sigmoidf_(a1)*Bp[off+tid+256]; }
  float mean = block_sum(a0+a1, lds) * (1.f/512.f);
  float d0=a0-mean, d1=a1-mean;
  float var = block_sum(d0*d0+d1*d1, lds) * (1.f/512.f);
  float rstd = rsqrtf(var + 1e-5f);
  float r0 = d0*rstd*g[tid]     + be[tid];
  float r1 = d1*rstd*g[tid+256] + be[tid+256];
  if (WF32){ outf[off+tid] = r0; outf[off+tid+256] = r1; }
  if (WB16){ outb[off+tid] = f2b(r0); outb[off+tid+256] = f2b(r1); }
}

// ---------- fused: x1 = LN(A+B); then scan prep from x1 ----------
// writes x1 (fp32), decay (may alias A), u (may alias B), dm, es
__global__ __launch_bounds__(256) void ln_scan_k(const float* A, const float* Bp,
    const float* __restrict__ g, const float* __restrict__ be, const float* __restrict__ tm,
    float* __restrict__ x1out, float* dec, float* u,
    float* __restrict__ dm, float* __restrict__ es){
  __shared__ float lds[4];
  const size_t row = blockIdx.x;
  const size_t off = row * D_MODEL;
  const int tid = threadIdx.x;
  float a0 = A[off+tid] + Bp[off+tid];
  float a1 = A[off+tid+256] + Bp[off+tid+256];
  float mean = block_sum(a0+a1, lds) * (1.f/512.f);
  float d0=a0-mean, d1=a1-mean;
  float var = block_sum(d0*d0+d1*d1, lds) * (1.f/512.f);
  float rstd = rsqrtf(var + 1e-5f);
  float r0 = d0*rstd*g[tid]     + be[tid];
  float r1 = d1*rstd*g[tid+256] + be[tid+256];
  x1out[off+tid] = r0; x1out[off+tid+256] = r1;
  float dc0 = sigmoidf_(r0*tm[tid]), dc1 = sigmoidf_(r1*tm[tid+256]);
  float e0 = expf(r0), e1 = expf(r1);
  dec[off+tid]=dc0; dec[off+tid+256]=dc1;
  u[off+tid]=e0*r0; u[off+tid+256]=e1*r1;
  float dsum = block_sum(dc0+dc1, lds);
  float esum = block_sum(e0+e1, lds);
  if (tid==0){ dm[row]=dsum*(1.f/512.f); es[row]=esum; }
}

// ---------- fused: coupled = LN(sigmoid(R)*V); x2 = LN(X1 + coupled) ----------
__global__ __launch_bounds__(256) void ln2x_k(const float* R, const float* V, const float* X1,
    const float* __restrict__ g1, const float* __restrict__ b1_,
    const float* __restrict__ g2, const float* __restrict__ b2_,
    float* x2f, unsigned short* __restrict__ x2b){
  __shared__ float lds[4];
  const size_t off = (size_t)blockIdx.x * D_MODEL;
  const int tid = threadIdx.x;
  float a0 = sigmoidf_(R[off+tid])*V[off+tid];
  float a1 = sigmoidf_(R[off+tid+256])*V[off+tid+256];
  float mean = block_sum(a0+a1, lds) * (1.f/512.f);
  float d0=a0-mean, d1=a1-mean;
  float var = block_sum(d0*d0+d1*d1, lds) * (1.f/512.f);
  float rstd = rsqrtf(var + 1e-5f);
  float c0 = d0*rstd*g1[tid]     + b1_[tid];
  float c1 = d1*rstd*g1[tid+256] + b1_[tid+256];
  // second LN on x1 + coupled
  float t0 = X1[off+tid] + c0, t1 = X1[off+tid+256] + c1;
  float mean2 = block_sum(t0+t1, lds) * (1.f/512.f);
  float e0=t0-mean2, e1=t1-mean2;
  float var2 = block_sum(e0*e0+e1*e1, lds) * (1.f/512.f);
  float rstd2 = rsqrtf(var2 + 1e-5f);
  float r0 = e0*rstd2*g2[tid]     + b2_[tid];
  float r1 = e1*rstd2*g2[tid+256] + b2_[tid+256];
  x2f[off+tid] = r0; x2f[off+tid+256] = r1;
  x2b[off+tid] = f2b(r0); x2b[off+tid+256] = f2b(r1);
}

// ---------- scalar 'a' scan per batch ----------
__global__ __launch_bounds__(256) void ascan_k(const float* __restrict__ dm, const float* __restrict__ es,
                                               float* __restrict__ a_out){
  __shared__ float sG[256], sU[256];
  const int b = blockIdx.x, tid = threadIdx.x;
  const float* dmb = dm + (size_t)b*SEQ;
  const float* esb = es + (size_t)b*SEQ;
  const int t0 = tid*8;
  float gi[8], ui[8];
  #pragma unroll
  for (int i=0;i<8;++i){ gi[i]=dmb[t0+i]; ui[i]=esb[t0+i]; }
  float G=1.f, U=0.f;
  #pragma unroll
  for (int i=0;i<8;++i){ U = gi[i]*U + ui[i]; G *= gi[i]; }
  sG[tid]=G; sU[tid]=U;
  __syncthreads();
  for (int off=1; off<256; off<<=1){
    float pg=1.f, pu=0.f;
    bool act = tid >= off;
    if (act){ pg = sG[tid-off]; pu = sU[tid-off]; }
    __syncthreads();
    if (act){ sU[tid] = sG[tid]*pu + sU[tid]; sG[tid] = sG[tid]*pg; }
    __syncthreads();
  }
  float a = (tid==0) ? 0.f : sU[tid-1];
  #pragma unroll
  for (int i=0;i<8;++i){ a = gi[i]*a + ui[i]; a_out[(size_t)b*SEQ + t0 + i] = a; }
}

// ---------- b scan: chunked ----------
__global__ __launch_bounds__(512) void bscan_p1(const float* __restrict__ decay, const float* __restrict__ u,
    float* __restrict__ Gc, float* __restrict__ Uc){
  const int c = blockIdx.x, b = blockIdx.y, d = threadIdx.x;
  size_t base = ((size_t)b*SEQ + (size_t)c*CHUNK)*D_MODEL + d;
  float G=1.f, U=0.f;
  for (int i=0;i<CHUNK;++i){
    float g  = decay[base + (size_t)i*D_MODEL];
    float uu = u[base + (size_t)i*D_MODEL];
    U = g*U + uu; G = g*G;
  }
  size_t idx = ((size_t)b*NCHUNK + c)*D_MODEL + d;
  Gc[idx]=G; Uc[idx]=U;
}
__global__ __launch_bounds__(512) void bscan_p2(const float* __restrict__ Gc, const float* __restrict__ Uc,
                                                float* __restrict__ binit){
  const int b = blockIdx.x, d = threadIdx.x;
  float cur = 0.f;
  for (int c=0;c<NCHUNK;++c){
    size_t idx = ((size_t)b*NCHUNK + c)*D_MODEL + d;
    binit[idx] = cur;
    cur = Gc[idx]*cur + Uc[idx];
  }
}
// u and outs may alias (in-place)
__global__ __launch_bounds__(512) void bscan_p3(const float* __restrict__ decay, const float* u,
    const float* __restrict__ binit, const float* __restrict__ a, float* outs){
  const int c = blockIdx.x, b = blockIdx.y, d = threadIdx.x;
  size_t base = ((size_t)b*SEQ + (size_t)c*CHUNK)*D_MODEL + d;
  float bv = binit[((size_t)b*NCHUNK + c)*D_MODEL + d];
  for (int i=0;i<CHUNK;++i){
    float g  = decay[base + (size_t)i*D_MODEL];
    float uu = u[base + (size_t)i*D_MODEL];
    bv = g*bv + uu;
    float av = a[(size_t)b*SEQ + (size_t)c*CHUNK + i];
    outs[base + (size_t)i*D_MODEL] = bv / (av + 1e-8f);
  }
}

extern "C" void kernel_launch(void* const* d_in, const int* in_sizes, int n_in,
                              void* d_out, int out_size, void* d_ws, size_t ws_size,
                              hipStream_t stream){
  const float* x     = (const float*)d_in[0];
  const float* xp    = (const float*)d_in[1];
  const float* mu    = (const float*)d_in[2];
  const float* in_w  = (const float*)d_in[3];
  const float* in_b  = (const float*)d_in[4];
  const float* out_w = (const float*)d_in[5];
  const float* out_b = (const float*)d_in[6];
  const float* ln1_g = (const float*)d_in[7];
  const float* ln1_b = (const float*)d_in[8];
  const float* tm    = (const float*)d_in[9];
  const float* sm_g  = (const float*)d_in[10];
  const float* sm_b  = (const float*)d_in[11];
  const float* wr_w  = (const float*)d_in[12];
  const float* wr_b  = (const float*)d_in[13];
  const float* wv_w  = (const float*)d_in[14];
  const float* wv_b  = (const float*)d_in[15];
  const float* sc_g  = (const float*)d_in[16];
  const float* sc_b  = (const float*)d_in[17];
  const float* ln2_g = (const float*)d_in[18];
  const float* ln2_b = (const float*)d_in[19];
  const float* w1    = (const float*)d_in[20];
  const float* b1    = (const float*)d_in[21];
  const float* w2    = (const float*)d_in[22];
  const float* b2    = (const float*)d_in[23];
  const float* ln3_g = (const float*)d_in[24];
  const float* ln3_b = (const float*)d_in[25];
  float* out = (float*)d_out;
  float* ws  = (float*)d_ws;

  const size_t N = (size_t)M_TOK*D_MODEL;   // 4,194,304
  float* S0f = ws;
  float* S1f = ws + N;
  float* S2f = ws + 2*N;
  float* EX  = ws + 3*N;
  float* dm    = EX;
  float* es    = EX + 8192;
  float* aarr  = EX + 16384;
  float* Gc    = EX + 24576;
  float* Uc    = Gc + 131072;
  float* binit = Uc + 131072;

  unsigned short* SB = (unsigned short*)(ws + 3*N + N/4);
  unsigned short* Wq = SB;
  unsigned short* Wo = Wq + 786432;
  unsigned short* Wr = Wo + 262144;
  unsigned short* Wv = Wr + 262144;
  unsigned short* W1 = Wv + 262144;
  unsigned short* W2 = W1 + 1048576;
  unsigned short* Xb = W2 + 1048576;
  unsigned short* Mb = Xb + N;
  unsigned short* U  = Mb + N;
  unsigned short* Qb  = U;
  unsigned short* AOb = U + 12*1024*1024;
  unsigned short* Hb  = U;

  // weight conversions
  cvt_k<<<768, 256, 0, stream>>>(in_w,  Wq, 196608);
  cvt_k<<<256, 256, 0, stream>>>(out_w, Wo, 65536);
  cvt_k<<<256, 256, 0, stream>>>(wr_w,  Wr, 65536);
  cvt_k<<<256, 256, 0, stream>>>(wv_w,  Wv, 65536);
  cvt_k<<<1024,256, 0, stream>>>(w1,    W1, 262144);
  cvt_k<<<1024,256, 0, stream>>>(w2,    W2, 262144);
  // 1. shifted -> S0f + Xb
  shift2_k<<<4096, 256, 0, stream>>>(x, xp, mu, S0f, Xb, (int)(N/4));
  // 2. qkv -> Qb
  mgemm_k<0,1><<<dim3(12,64), 256, 0, stream>>>(Xb, Wq, in_b, nullptr, Qb, 1536, 512);
  // 3. flash attention -> AOb
  fattn_k<<<dim3(SEQ/128, NH, BATCH), 256, 0, stream>>>(Qb, AOb);
  // 4. out-proj -> S1f
  mgemm_k<0,0><<<dim3(4,64), 256, 0, stream>>>(AOb, Wo, out_b, S1f, nullptr, 512, 512);
  // 5+6. x1 = LN(shifted+proj) -> S2f; decay -> S0f; u -> S1f; dm/es
  ln_scan_k<<<M_TOK, 256, 0, stream>>>(S0f, S1f, ln1_g, ln1_b, tm, S2f, S0f, S1f, dm, es);
  // 7. 'a' scan
  ascan_k<<<BATCH, 256, 0, stream>>>(dm, es, aarr);
  // 8-10. 'b' scan -> outs (in-place over u = S1f)
  bscan_p1<<<dim3(NCHUNK, BATCH), 512, 0, stream>>>(S0f, S1f, Gc, Uc);
  bscan_p2<<<BATCH, 512, 0, stream>>>(Gc, Uc, binit);
  bscan_p3<<<dim3(NCHUNK, BATCH), 512, 0, stream>>>(S0f, S1f, binit, aarr, S1f);
  // 11. merged = LN(outs) -> Mb
  ln_k<0,0,1><<<M_TOK, 256, 0, stream>>>(S1f, nullptr, sm_g, sm_b, nullptr, Mb);
  // 12. r -> S0f, v -> S1f
  mgemm_k<0,0><<<dim3(4,64), 256, 0, stream>>>(Mb, Wr, wr_b, S0f, nullptr, 512, 512);
  mgemm_k<0,0><<<dim3(4,64), 256, 0, stream>>>(Mb, Wv, wv_b, S1f, nullptr, 512, 512);
  // 13+14. coupled = LN(sigmoid(r)*v); x2 = LN(x1+coupled) -> S0f + Xb
  ln2x_k<<<M_TOK, 256, 0, stream>>>(S0f, S1f, S2f, sc_g, sc_b, ln2_g, ln2_b, S0f, Xb);
  // 15. hidden = relu(x2 @ w1.T + b1) -> Hb
  mgemm_k<1,1><<<dim3(16,64), 256, 0, stream>>>(Xb, W1, b1, nullptr, Hb, 2048, 512);
  // 16. ffnout -> S1f
  mgemm_k<0,0><<<dim3(4,64), 256, 0, stream>>>(Hb, W2, b2, S1f, nullptr, 512, 2048);
  // 17. out = LN(x2 + ffnout)
  ln_k<1,1,0><<<M_TOK, 256, 0, stream>>>(S0f, S1f, ln3_g, ln3_b, out, nullptr);
}

// Round 5
// 334.411 us; speedup vs baseline: 20.5754x; 1.1652x over previous
//
#include <hip/hip_runtime.h>
#include <math.h>

#define D_MODEL 512
#define SEQ     2048
#define BATCH   4
#define NH      8
#define HD      64
#define CHUNK   32
#define NCHUNK  64
#define M_TOK   (BATCH*SEQ)   // 8192

typedef __attribute__((ext_vector_type(8))) short bhalf8;   // 8 bf16 = 4 VGPR
typedef __attribute__((ext_vector_type(4))) float f32x4;

__device__ __forceinline__ float sigmoidf_(float x){ return 1.f/(1.f+expf(-x)); }

__device__ __forceinline__ unsigned short f2b(float f){   // fp32 -> bf16 RNE
  unsigned u = __float_as_uint(f);
  u += 0x7FFFu + ((u>>16)&1u);
  return (unsigned short)(u>>16);
}

__device__ __forceinline__ void gll16(const void* g, void* l){
  __builtin_amdgcn_global_load_lds(
      (const __attribute__((address_space(1))) unsigned int*)g,
      (__attribute__((address_space(3))) unsigned int*)l, 16, 0, 0);
}

// ---------- block reduction ----------
__device__ __forceinline__ float block_sum(float v, float* lds){
  #pragma unroll
  for (int o=32;o>0;o>>=1) v += __shfl_xor(v,o);
  int w = threadIdx.x>>6, l = threadIdx.x&63;
  if (l==0) lds[w]=v;
  __syncthreads();
  float t=0.f; int nw = blockDim.x>>6;
  for (int i=0;i<nw;++i) t+=lds[i];
  __syncthreads();
  return t;
}

// ---------- fp32 -> bf16 weight convert ----------
__global__ void cvt_k(const float* __restrict__ s, unsigned short* __restrict__ d, int n4){
  int i = blockIdx.x*blockDim.x + threadIdx.x;
  if (i < n4){
    float4 v = ((const float4*)s)[i];
    unsigned a=f2b(v.x), b=f2b(v.y), c=f2b(v.z), e=f2b(v.w);
    uint2 p; p.x = a | (b<<16); p.y = c | (e<<16);
    ((uint2*)d)[i] = p;
  }
}

// ---------- shift: fp32 out + bf16 out ----------
__global__ void shift2_k(const float* __restrict__ x, const float* __restrict__ xp,
                         const float* __restrict__ mu, float* __restrict__ of,
                         unsigned short* __restrict__ ob, int n4){
  int i = blockIdx.x*blockDim.x + threadIdx.x;
  if (i < n4){
    float m = mu[0];
    float4 a = ((const float4*)x)[i], p = ((const float4*)xp)[i];
    float4 r;
    r.x = m*a.x + (1.f-m)*p.x; r.y = m*a.y + (1.f-m)*p.y;
    r.z = m*a.z + (1.f-m)*p.z; r.w = m*a.w + (1.f-m)*p.w;
    ((float4*)of)[i] = r;
    unsigned A=f2b(r.x), B=f2b(r.y), C=f2b(r.z), E=f2b(r.w);
    uint2 q; q.x = A | (B<<16); q.y = C | (E<<16);
    ((uint2*)ob)[i] = q;
  }
}

// ---------- bf16 MFMA GEMM 128x128 (verified) ----------
template<int ACT, int OUTB>
__global__ __launch_bounds__(256) void mgemm_k(const unsigned short* __restrict__ A,
    const unsigned short* __restrict__ W, const float* __restrict__ bias,
    float* __restrict__ Yf, unsigned short* __restrict__ Yb, int Nd, int K){
  __shared__ unsigned short As[128*64];
  __shared__ unsigned short Bs[128*64];
  const int tid = threadIdx.x;
  const int w = tid>>6, lane = tid&63;
  const int l15 = lane&15, l4 = lane>>4;
  const int wr = w>>1, wc = w&1;
  const int bn = blockIdx.x, bm = blockIdx.y;

  const size_t Kb = (size_t)K*2;
  const int srow  = lane>>3;
  const int sbyte = ((lane&7)*16) ^ (srow<<4);
  const char* Ag = (const char*)A + (size_t)(bm*128)*Kb + sbyte;
  const char* Wg = (const char*)W + (size_t)(bn*128)*Kb + sbyte;

  f32x4 acc[4][4];
  const f32x4 z = {0.f,0.f,0.f,0.f};
  #pragma unroll
  for (int i=0;i<4;++i)
    #pragma unroll
    for (int j=0;j<4;++j) acc[i][j] = z;

  const int KT = K/64;
  for (int kt=0; kt<KT; ++kt){
    if (kt) __syncthreads();
    const size_t kOff = (size_t)kt*128;
    #pragma unroll
    for (int i=0;i<4;++i){
      int c = w*4 + i;
      int r = c*8 + srow;
      gll16(Ag + (size_t)r*Kb + kOff, (char*)As + c*1024);
      gll16(Wg + (size_t)r*Kb + kOff, (char*)Bs + c*1024);
    }
    __syncthreads();

    bhalf8 af[4][2], bf_[4][2];
    #pragma unroll
    for (int fr=0; fr<4; ++fr){
      int row = wr*64 + fr*16 + l15;
      #pragma unroll
      for (int ks=0; ks<2; ++ks){
        int byo = (l4*16 + ks*64) ^ ((row&7)<<4);
        af[fr][ks] = *(const bhalf8*)((const char*)As + row*128 + byo);
      }
    }
    #pragma unroll
    for (int fc=0; fc<4; ++fc){
      int row = wc*64 + fc*16 + l15;
      #pragma unroll
      for (int ks=0; ks<2; ++ks){
        int byo = (l4*16 + ks*64) ^ ((row&7)<<4);
        bf_[fc][ks] = *(const bhalf8*)((const char*)Bs + row*128 + byo);
      }
    }
    #pragma unroll
    for (int ks=0; ks<2; ++ks)
      #pragma unroll
      for (int fr=0; fr<4; ++fr)
        #pragma unroll
        for (int fc=0; fc<4; ++fc)
          acc[fr][fc] = __builtin_amdgcn_mfma_f32_16x16x32_bf16(af[fr][ks], bf_[fc][ks], acc[fr][fc], 0, 0, 0);
  }

  const int rowBase = bm*128 + wr*64;
  const int colBase = bn*128 + wc*64;
  #pragma unroll
  for (int fc=0; fc<4; ++fc){
    int col = colBase + fc*16 + l15;
    float bv = bias[col];
    #pragma unroll
    for (int fr=0; fr<4; ++fr){
      #pragma unroll
      for (int j=0; j<4; ++j){
        int row = rowBase + fr*16 + l4*4 + j;
        float v = acc[fr][fc][j] + bv;
        if (ACT) v = fmaxf(v, 0.f);
        if (OUTB) Yb[(size_t)row*Nd + col] = f2b(v);
        else      Yf[(size_t)row*Nd + col] = v;
      }
    }
  }
}

// ---------- bf16 MFMA GEMM 128x64 (for N=512: doubles grid to 512 blocks) ----------
template<int ACT, int OUTB>
__global__ __launch_bounds__(256) void mgemm64_k(const unsigned short* __restrict__ A,
    const unsigned short* __restrict__ W, const float* __restrict__ bias,
    float* __restrict__ Yf, unsigned short* __restrict__ Yb, int Nd, int K){
  __shared__ unsigned short As[128*64];
  __shared__ unsigned short Bs[64*64];
  const int tid = threadIdx.x;
  const int w = tid>>6, lane = tid&63;
  const int l15 = lane&15, l4 = lane>>4;
  const int wr = w>>1, wc = w&1;
  const int bn = blockIdx.x, bm = blockIdx.y;

  const size_t Kb = (size_t)K*2;
  const int srow  = lane>>3;
  const int sbyte = ((lane&7)*16) ^ (srow<<4);
  const char* Ag = (const char*)A + (size_t)(bm*128)*Kb + sbyte;
  const char* Wg = (const char*)W + (size_t)(bn*64)*Kb + sbyte;

  f32x4 acc[4][2];
  const f32x4 z = {0.f,0.f,0.f,0.f};
  #pragma unroll
  for (int i=0;i<4;++i)
    #pragma unroll
    for (int j=0;j<2;++j) acc[i][j] = z;

  const int KT = K/64;
  for (int kt=0; kt<KT; ++kt){
    if (kt) __syncthreads();
    const size_t kOff = (size_t)kt*128;
    #pragma unroll
    for (int i=0;i<4;++i){
      int c = w*4 + i;
      int r = c*8 + srow;
      gll16(Ag + (size_t)r*Kb + kOff, (char*)As + c*1024);
    }
    #pragma unroll
    for (int i=0;i<2;++i){
      int c = w*2 + i;
      int r = c*8 + srow;
      gll16(Wg + (size_t)r*Kb + kOff, (char*)Bs + c*1024);
    }
    __syncthreads();

    bhalf8 af[4][2], bf_[2][2];
    #pragma unroll
    for (int fr=0; fr<4; ++fr){
      int row = wr*64 + fr*16 + l15;
      #pragma unroll
      for (int ks=0; ks<2; ++ks){
        int byo = (l4*16 + ks*64) ^ ((row&7)<<4);
        af[fr][ks] = *(const bhalf8*)((const char*)As + row*128 + byo);
      }
    }
    #pragma unroll
    for (int fc=0; fc<2; ++fc){
      int row = wc*32 + fc*16 + l15;
      #pragma unroll
      for (int ks=0; ks<2; ++ks){
        int byo = (l4*16 + ks*64) ^ ((row&7)<<4);
        bf_[fc][ks] = *(const bhalf8*)((const char*)Bs + row*128 + byo);
      }
    }
    #pragma unroll
    for (int ks=0; ks<2; ++ks)
      #pragma unroll
      for (int fr=0; fr<4; ++fr)
        #pragma unroll
        for (int fc=0; fc<2; ++fc)
          acc[fr][fc] = __builtin_amdgcn_mfma_f32_16x16x32_bf16(af[fr][ks], bf_[fc][ks], acc[fr][fc], 0, 0, 0);
  }

  const int rowBase = bm*128 + wr*64;
  const int colBase = bn*64 + wc*32;
  #pragma unroll
  for (int fc=0; fc<2; ++fc){
    int col = colBase + fc*16 + l15;
    float bv = bias[col];
    #pragma unroll
    for (int fr=0; fr<4; ++fr){
      #pragma unroll
      for (int j=0; j<4; ++j){
        int row = rowBase + fr*16 + l4*4 + j;
        float v = acc[fr][fc][j] + bv;
        if (ACT) v = fmaxf(v, 0.f);
        if (OUTB) Yb[(size_t)row*Nd + col] = f2b(v);
        else      Yf[(size_t)row*Nd + col] = v;
      }
    }
  }
}

// ---------- bf16 MFMA flash attention: 8 waves, QBLK=128, 1 subtile/wave ----------
// block = (qt, h, b). Wave w owns q rows qt*128 + w*16 + [0,16).
// Swapped QK: S^T via mfma(K,Q) -> lane holds S[kv=fc*16+l4*4+j][q=l15].
__global__ __launch_bounds__(512, 4) void fattn_k(const unsigned short* __restrict__ qkv,
                                                  unsigned short* __restrict__ ao){
  __shared__ unsigned short Ks[2][64*64];
  __shared__ unsigned short Vt[2][64*64];
  __shared__ unsigned short Ps[128*64];
  const int qt = blockIdx.x, h = blockIdx.y, b = blockIdx.z;
  const int tid = threadIdx.x, w = tid>>6, lane = tid&63;
  const int l15 = lane&15, l4 = lane>>4;
  const size_t rowB = 3072;                 // 1536 bf16 per token row
  const char* base = (const char*)qkv + (size_t)b*SEQ*rowB;
  const char* Kg = base + 1024 + h*128;
  const char* Vg = base + 2048 + h*128;

  // Q fragment (B-operand): q = qt*128 + w*16 + l15, hd = ks*32 + l4*8 + e
  bhalf8 qf[2];
  {
    const char* qrow = base + (size_t)(qt*128 + w*16 + l15)*rowB + h*128;
    qf[0] = *(const bhalf8*)(qrow + l4*16);
    qf[1] = *(const bhalf8*)(qrow + l4*16 + 64);
  }

  const f32x4 z = {0.f,0.f,0.f,0.f};
  f32x4 oa[4];
  #pragma unroll
  for (int i=0;i<4;++i) oa[i] = z;
  float mj = -INFINITY, lj = 0.f;

  const int srow  = lane>>3;
  const int sbyte = ((lane&7)*16) ^ (srow<<4);
  const int vd = lane;          // V column this thread handles (0..63)
  // wave w loads V kv-rows w*8 .. w*8+7

  unsigned vload[8];
  // prologue: stage tile 0
  {
    int r = w*8 + srow;
    gll16(Kg + (size_t)r*rowB + sbyte, (char*)Ks[0] + w*1024);
  }
  #pragma unroll
  for (int i=0;i<8;++i)
    vload[i] = *(const unsigned short*)(Vg + (size_t)(w*8 + i)*rowB + vd*2);

  int cur = 0;
  for (int kt=0; kt<SEQ/64; ++kt){
    // write Vt[cur] from regs: 2 clean b64 swizzled writes
    #pragma unroll
    for (int p=0;p<2;++p){
      unsigned lo = (vload[p*4+0]&0xFFFFu) | (vload[p*4+1]<<16);
      unsigned hi = (vload[p*4+2]&0xFFFFu) | (vload[p*4+3]<<16);
      uint2 pk; pk.x = lo; pk.y = hi;
      int byo = (w*16 + p*8) ^ ((vd&7)<<4);
      *(uint2*)((char*)Vt[cur] + vd*128 + byo) = pk;
    }
    __syncthreads();   // Ks[cur] gll16 drained + Vt[cur] visible

    if (kt+1 < SEQ/64){
      int r = w*8 + srow;
      gll16(Kg + (size_t)((kt+1)*64 + r)*rowB + sbyte, (char*)Ks[cur^1] + w*1024);
      #pragma unroll
      for (int i=0;i<8;++i)
        vload[i] = *(const unsigned short*)(Vg + (size_t)((kt+1)*64 + w*8 + i)*rowB + vd*2);
    }

    // ---- compute from buffers [cur] ----
    bhalf8 kf[4][2];
    #pragma unroll
    for (int fc=0; fc<4; ++fc){
      int kr = fc*16 + l15;
      #pragma unroll
      for (int ks=0; ks<2; ++ks){
        int byo = (l4*16 + ks*64) ^ ((kr&7)<<4);
        kf[fc][ks] = *(const bhalf8*)((const char*)Ks[cur] + kr*128 + byo);
      }
    }
    f32x4 s[4];
    #pragma unroll
    for (int i=0;i<4;++i) s[i] = z;
    #pragma unroll
    for (int ks=0; ks<2; ++ks)
      #pragma unroll
      for (int fc=0; fc<4; ++fc)
        s[fc] = __builtin_amdgcn_mfma_f32_16x16x32_bf16(kf[fc][ks], qf[ks], s[fc], 0, 0, 0);

    // online softmax (row q = l15; 16 kv per lane; reduce across l4 groups)
    {
      float rm = s[0][0];
      #pragma unroll
      for (int fc=0; fc<4; ++fc)
        #pragma unroll
        for (int j=0; j<4; ++j) rm = fmaxf(rm, s[fc][j]);
      rm = fmaxf(rm, __shfl_xor(rm,16));
      rm = fmaxf(rm, __shfl_xor(rm,32));
      float mn = fmaxf(mj, 0.125f*rm);
      float sc = __expf(mj-mn);
      float p[4][4];
      float rs = 0.f;
      #pragma unroll
      for (int fc=0; fc<4; ++fc)
        #pragma unroll
        for (int j=0; j<4; ++j){
          float e = __expf(fmaf(0.125f, s[fc][j], -mn));
          p[fc][j] = e; rs += e;
        }
      rs += __shfl_xor(rs,16);
      rs += __shfl_xor(rs,32);
      lj = lj*sc + rs;
      mj = mn;
      float scj0 = __shfl(sc, l4*4+0), scj1 = __shfl(sc, l4*4+1);
      float scj2 = __shfl(sc, l4*4+2), scj3 = __shfl(sc, l4*4+3);
      #pragma unroll
      for (int fc=0; fc<4; ++fc){
        oa[fc][0] *= scj0; oa[fc][1] *= scj1;
        oa[fc][2] *= scj2; oa[fc][3] *= scj3;
      }
      // pack P -> 4 clean b64 swizzled writes (wave-private rows)
      int qrow = w*16 + l15;
      #pragma unroll
      for (int fc=0; fc<4; ++fc){
        unsigned lo = (unsigned)f2b(p[fc][0]) | ((unsigned)f2b(p[fc][1])<<16);
        unsigned hi = (unsigned)f2b(p[fc][2]) | ((unsigned)f2b(p[fc][3])<<16);
        uint2 pk; pk.x = lo; pk.y = hi;
        int byo = (fc*32 + l4*8) ^ ((l15&7)<<4);
        *(uint2*)((char*)Ps + qrow*128 + byo) = pk;
      }
    }

    // V fragments (B-operand): lane holds V[kv=ks*32+l4*8+e][d=fc*16+l15]
    bhalf8 vf[4][2];
    #pragma unroll
    for (int fc=0; fc<4; ++fc){
      int d = fc*16 + l15;
      #pragma unroll
      for (int ks=0; ks<2; ++ks){
        int byo = (ks*64 + l4*16) ^ ((d&7)<<4);
        vf[fc][ks] = *(const bhalf8*)((const char*)Vt[cur] + d*128 + byo);
      }
    }
    // O += P V  (A = P: lane holds P[q=l15][kv=ks*32+l4*8+e])
    {
      int qrow = w*16 + l15;
      bhalf8 pf[2];
      #pragma unroll
      for (int ks=0; ks<2; ++ks){
        int byo = (ks*64 + l4*16) ^ ((l15&7)<<4);
        pf[ks] = *(const bhalf8*)((const char*)Ps + qrow*128 + byo);
      }
      #pragma unroll
      for (int ks=0; ks<2; ++ks)
        #pragma unroll
        for (int fc=0; fc<4; ++fc)
          oa[fc] = __builtin_amdgcn_mfma_f32_16x16x32_bf16(pf[ks], vf[fc][ks], oa[fc], 0, 0, 0);
    }
    cur ^= 1;
  }

  // epilogue: O[q = base + l4*4+j][d = fc*16+l15]
  {
    float linv = 1.f/lj;
    float li0 = __shfl(linv, l4*4+0), li1 = __shfl(linv, l4*4+1);
    float li2 = __shfl(linv, l4*4+2), li3 = __shfl(linv, l4*4+3);
    #pragma unroll
    for (int fc=0; fc<4; ++fc){
      int col = h*64 + fc*16 + l15;
      size_t r0 = (size_t)(b*SEQ + qt*128 + w*16 + l4*4);
      ao[(r0+0)*D_MODEL + col] = f2b(oa[fc][0]*li0);
      ao[(r0+1)*D_MODEL + col] = f2b(oa[fc][1]*li1);
      ao[(r0+2)*D_MODEL + col] = f2b(oa[fc][2]*li2);
      ao[(r0+3)*D_MODEL + col] = f2b(oa[fc][3]*li3);
    }
  }
}

// ---------- LayerNorm over D=512; MODE 0: A, 1: A+B, 2: sigmoid(A)*B ----------
template<int MODE, int WF32, int WB16>
__global__ __launch_bounds__(256) void ln_k(const float* A, const float* Bp,
    const float* g, const float* be, float* outf, unsigned short* outb){
  __shared__ float lds[4];
  const size_t off = (size_t)blockIdx.x * D_MODEL;
  const int tid = threadIdx.x;
  float a0 = A[off+tid], a1 = A[off+tid+256];
  if (MODE==1){ a0 += Bp[off+tid]; a1 += Bp[off+tid+256]; }
  if (MODE==2){ a0 = sigmoidf_(a0)*Bp[off+tid]; a1 = sigmoidf_(a1)*Bp[off+tid+256]; }
  float mean = block_sum(a0+a1, lds) * (1.f/512.f);
  float d0=a0-mean, d1=a1-mean;
  float var = block_sum(d0*d0+d1*d1, lds) * (1.f/512.f);
  float rstd = rsqrtf(var + 1e-5f);
  float r0 = d0*rstd*g[tid]     + be[tid];
  float r1 = d1*rstd*g[tid+256] + be[tid+256];
  if (WF32){ outf[off+tid] = r0; outf[off+tid+256] = r1; }
  if (WB16){ outb[off+tid] = f2b(r0); outb[off+tid+256] = f2b(r1); }
}

// ---------- fused: x1 = LN(A+B); then scan prep from x1 ----------
__global__ __launch_bounds__(256) void ln_scan_k(const float* A, const float* Bp,
    const float* __restrict__ g, const float* __restrict__ be, const float* __restrict__ tm,
    float* __restrict__ x1out, float* dec, float* u,
    float* __restrict__ dm, float* __restrict__ es){
  __shared__ float lds[4];
  const size_t row = blockIdx.x;
  const size_t off = row * D_MODEL;
  const int tid = threadIdx.x;
  float a0 = A[off+tid] + Bp[off+tid];
  float a1 = A[off+tid+256] + Bp[off+tid+256];
  float mean = block_sum(a0+a1, lds) * (1.f/512.f);
  float d0=a0-mean, d1=a1-mean;
  float var = block_sum(d0*d0+d1*d1, lds) * (1.f/512.f);
  float rstd = rsqrtf(var + 1e-5f);
  float r0 = d0*rstd*g[tid]     + be[tid];
  float r1 = d1*rstd*g[tid+256] + be[tid+256];
  x1out[off+tid] = r0; x1out[off+tid+256] = r1;
  float dc0 = sigmoidf_(r0*tm[tid]), dc1 = sigmoidf_(r1*tm[tid+256]);
  float e0 = expf(r0), e1 = expf(r1);
  dec[off+tid]=dc0; dec[off+tid+256]=dc1;
  u[off+tid]=e0*r0; u[off+tid+256]=e1*r1;
  float dsum = block_sum(dc0+dc1, lds);
  float esum = block_sum(e0+e1, lds);
  if (tid==0){ dm[row]=dsum*(1.f/512.f); es[row]=esum; }
}

// ---------- fused: coupled = LN(sigmoid(R)*V); x2 = LN(X1 + coupled) ----------
__global__ __launch_bounds__(256) void ln2x_k(const float* R, const float* V, const float* X1,
    const float* __restrict__ g1, const float* __restrict__ b1_,
    const float* __restrict__ g2, const float* __restrict__ b2_,
    float* x2f, unsigned short* __restrict__ x2b){
  __shared__ float lds[4];
  const size_t off = (size_t)blockIdx.x * D_MODEL;
  const int tid = threadIdx.x;
  float a0 = sigmoidf_(R[off+tid])*V[off+tid];
  float a1 = sigmoidf_(R[off+tid+256])*V[off+tid+256];
  float mean = block_sum(a0+a1, lds) * (1.f/512.f);
  float d0=a0-mean, d1=a1-mean;
  float var = block_sum(d0*d0+d1*d1, lds) * (1.f/512.f);
  float rstd = rsqrtf(var + 1e-5f);
  float c0 = d0*rstd*g1[tid]     + b1_[tid];
  float c1 = d1*rstd*g1[tid+256] + b1_[tid+256];
  float t0 = X1[off+tid] + c0, t1 = X1[off+tid+256] + c1;
  float mean2 = block_sum(t0+t1, lds) * (1.f/512.f);
  float e0=t0-mean2, e1=t1-mean2;
  float var2 = block_sum(e0*e0+e1*e1, lds) * (1.f/512.f);
  float rstd2 = rsqrtf(var2 + 1e-5f);
  float r0 = e0*rstd2*g2[tid]     + b2_[tid];
  float r1 = e1*rstd2*g2[tid+256] + b2_[tid+256];
  x2f[off+tid] = r0; x2f[off+tid+256] = r1;
  x2b[off+tid] = f2b(r0); x2b[off+tid+256] = f2b(r1);
}

// ---------- scalar 'a' scan per batch ----------
__global__ __launch_bounds__(256) void ascan_k(const float* __restrict__ dm, const float* __restrict__ es,
                                               float* __restrict__ a_out){
  __shared__ float sG[256], sU[256];
  const int b = blockIdx.x, tid = threadIdx.x;
  const float* dmb = dm + (size_t)b*SEQ;
  const float* esb = es + (size_t)b*SEQ;
  const int t0 = tid*8;
  float gi[8], ui[8];
  #pragma unroll
  for (int i=0;i<8;++i){ gi[i]=dmb[t0+i]; ui[i]=esb[t0+i]; }
  float G=1.f, U=0.f;
  #pragma unroll
  for (int i=0;i<8;++i){ U = gi[i]*U + ui[i]; G *= gi[i]; }
  sG[tid]=G; sU[tid]=U;
  __syncthreads();
  for (int off=1; off<256; off<<=1){
    float pg=1.f, pu=0.f;
    bool act = tid >= off;
    if (act){ pg = sG[tid-off]; pu = sU[tid-off]; }
    __syncthreads();
    if (act){ sU[tid] = sG[tid]*pu + sU[tid]; sG[tid] = sG[tid]*pg; }
    __syncthreads();
  }
  float a = (tid==0) ? 0.f : sU[tid-1];
  #pragma unroll
  for (int i=0;i<8;++i){ a = gi[i]*a + ui[i]; a_out[(size_t)b*SEQ + t0 + i] = a; }
}

// ---------- b scan: chunked ----------
__global__ __launch_bounds__(512) void bscan_p1(const float* __restrict__ decay, const float* __restrict__ u,
    float* __restrict__ Gc, float* __restrict__ Uc){
  const int c = blockIdx.x, b = blockIdx.y, d = threadIdx.x;
  size_t base = ((size_t)b*SEQ + (size_t)c*CHUNK)*D_MODEL + d;
  float G=1.f, U=0.f;
  for (int i=0;i<CHUNK;++i){
    float g  = decay[base + (size_t)i*D_MODEL];
    float uu = u[base + (size_t)i*D_MODEL];
    U = g*U + uu; G = g*G;
  }
  size_t idx = ((size_t)b*NCHUNK + c)*D_MODEL + d;
  Gc[idx]=G; Uc[idx]=U;
}
__global__ __launch_bounds__(512) void bscan_p2(const float* __restrict__ Gc, const float* __restrict__ Uc,
                                                float* __restrict__ binit){
  const int b = blockIdx.x, d = threadIdx.x;
  float cur = 0.f;
  for (int c=0;c<NCHUNK;++c){
    size_t idx = ((size_t)b*NCHUNK + c)*D_MODEL + d;
    binit[idx] = cur;
    cur = Gc[idx]*cur + Uc[idx];
  }
}
// u and outs may alias (in-place)
__global__ __launch_bounds__(512) void bscan_p3(const float* __restrict__ decay, const float* u,
    const float* __restrict__ binit, const float* __restrict__ a, float* outs){
  const int c = blockIdx.x, b = blockIdx.y, d = threadIdx.x;
  size_t base = ((size_t)b*SEQ + (size_t)c*CHUNK)*D_MODEL + d;
  float bv = binit[((size_t)b*NCHUNK + c)*D_MODEL + d];
  for (int i=0;i<CHUNK;++i){
    float g  = decay[base + (size_t)i*D_MODEL];
    float uu = u[base + (size_t)i*D_MODEL];
    bv = g*bv + uu;
    float av = a[(size_t)b*SEQ + (size_t)c*CHUNK + i];
    outs[base + (size_t)i*D_MODEL] = bv / (av + 1e-8f);
  }
}

extern "C" void kernel_launch(void* const* d_in, const int* in_sizes, int n_in,
                              void* d_out, int out_size, void* d_ws, size_t ws_size,
                              hipStream_t stream){
  const float* x     = (const float*)d_in[0];
  const float* xp    = (const float*)d_in[1];
  const float* mu    = (const float*)d_in[2];
  const float* in_w  = (const float*)d_in[3];
  const float* in_b  = (const float*)d_in[4];
  const float* out_w = (const float*)d_in[5];
  const float* out_b = (const float*)d_in[6];
  const float* ln1_g = (const float*)d_in[7];
  const float* ln1_b = (const float*)d_in[8];
  const float* tm    = (const float*)d_in[9];
  const float* sm_g  = (const float*)d_in[10];
  const float* sm_b  = (const float*)d_in[11];
  const float* wr_w  = (const float*)d_in[12];
  const float* wr_b  = (const float*)d_in[13];
  const float* wv_w  = (const float*)d_in[14];
  const float* wv_b  = (const float*)d_in[15];
  const float* sc_g  = (const float*)d_in[16];
  const float* sc_b  = (const float*)d_in[17];
  const float* ln2_g = (const float*)d_in[18];
  const float* ln2_b = (const float*)d_in[19];
  const float* w1    = (const float*)d_in[20];
  const float* b1    = (const float*)d_in[21];
  const float* w2    = (const float*)d_in[22];
  const float* b2    = (const float*)d_in[23];
  const float* ln3_g = (const float*)d_in[24];
  const float* ln3_b = (const float*)d_in[25];
  float* out = (float*)d_out;
  float* ws  = (float*)d_ws;

  const size_t N = (size_t)M_TOK*D_MODEL;   // 4,194,304
  float* S0f = ws;
  float* S1f = ws + N;
  float* S2f = ws + 2*N;
  float* EX  = ws + 3*N;
  float* dm    = EX;
  float* es    = EX + 8192;
  float* aarr  = EX + 16384;
  float* Gc    = EX + 24576;
  float* Uc    = Gc + 131072;
  float* binit = Uc + 131072;

  unsigned short* SB = (unsigned short*)(ws + 3*N + N/4);
  unsigned short* Wq = SB;
  unsigned short* Wo = Wq + 786432;
  unsigned short* Wr = Wo + 262144;
  unsigned short* Wv = Wr + 262144;
  unsigned short* W1 = Wv + 262144;
  unsigned short* W2 = W1 + 1048576;
  unsigned short* Xb = W2 + 1048576;
  unsigned short* Mb = Xb + N;
  unsigned short* U  = Mb + N;
  unsigned short* Qb  = U;
  unsigned short* AOb = U + 12*1024*1024;
  unsigned short* Hb  = U;

  // weight conversions
  cvt_k<<<768, 256, 0, stream>>>(in_w,  Wq, 196608);
  cvt_k<<<256, 256, 0, stream>>>(out_w, Wo, 65536);
  cvt_k<<<256, 256, 0, stream>>>(wr_w,  Wr, 65536);
  cvt_k<<<256, 256, 0, stream>>>(wv_w,  Wv, 65536);
  cvt_k<<<1024,256, 0, stream>>>(w1,    W1, 262144);
  cvt_k<<<1024,256, 0, stream>>>(w2,    W2, 262144);
  // 1. shifted -> S0f + Xb
  shift2_k<<<4096, 256, 0, stream>>>(x, xp, mu, S0f, Xb, (int)(N/4));
  // 2. qkv -> Qb
  mgemm_k<0,1><<<dim3(12,64), 256, 0, stream>>>(Xb, Wq, in_b, nullptr, Qb, 1536, 512);
  // 3. flash attention -> AOb  (512 threads, 8 waves)
  fattn_k<<<dim3(SEQ/128, NH, BATCH), 512, 0, stream>>>(Qb, AOb);
  // 4. out-proj -> S1f
  mgemm64_k<0,0><<<dim3(8,64), 256, 0, stream>>>(AOb, Wo, out_b, S1f, nullptr, 512, 512);
  // 5+6. x1 = LN(shifted+proj) -> S2f; decay -> S0f; u -> S1f; dm/es
  ln_scan_k<<<M_TOK, 256, 0, stream>>>(S0f, S1f, ln1_g, ln1_b, tm, S2f, S0f, S1f, dm, es);
  // 7. 'a' scan
  ascan_k<<<BATCH, 256, 0, stream>>>(dm, es, aarr);
  // 8-10. 'b' scan -> outs (in-place over u = S1f)
  bscan_p1<<<dim3(NCHUNK, BATCH), 512, 0, stream>>>(S0f, S1f, Gc, Uc);
  bscan_p2<<<BATCH, 512, 0, stream>>>(Gc, Uc, binit);
  bscan_p3<<<dim3(NCHUNK, BATCH), 512, 0, stream>>>(S0f, S1f, binit, aarr, S1f);
  // 11. merged = LN(outs) -> Mb
  ln_k<0,0,1><<<M_TOK, 256, 0, stream>>>(S1f, nullptr, sm_g, sm_b, nullptr, Mb);
  // 12. r -> S0f, v -> S1f
  mgemm64_k<0,0><<<dim3(8,64), 256, 0, stream>>>(Mb, Wr, wr_b, S0f, nullptr, 512, 512);
  mgemm64_k<0,0><<<dim3(8,64), 256, 0, stream>>>(Mb, Wv, wv_b, S1f, nullptr, 512, 512);
  // 13+14. coupled = LN(sigmoid(r)*v); x2 = LN(x1+coupled) -> S0f + Xb
  ln2x_k<<<M_TOK, 256, 0, stream>>>(S0f, S1f, S2f, sc_g, sc_b, ln2_g, ln2_b, S0f, Xb);
  // 15. hidden = relu(x2 @ w1.T + b1) -> Hb
  mgemm_k<1,1><<<dim3(16,64), 256, 0, stream>>>(Xb, W1, b1, nullptr, Hb, 2048, 512);
  // 16. ffnout -> S1f
  mgemm64_k<0,0><<<dim3(8,64), 256, 0, stream>>>(Hb, W2, b2, S1f, nullptr, 512, 2048);
  // 17. out = LN(x2 + ffnout)
  ln_k<1,1,0><<<M_TOK, 256, 0, stream>>>(S0f, S1f, ln3_g, ln3_b, out, nullptr);
}